// Round 6
// baseline (602.705 us; speedup 1.0000x reference)
//
#include <hip/hip_runtime.h>
#include <stdint.h>

#define N_V 100000
#define N_E 200000
#define NNZ 800000
#define D_IN 14
#define H 128

typedef __attribute__((ext_vector_type(2))) float f32x2;

__device__ __forceinline__ unsigned short f2bf(float f) {
  unsigned int u = __float_as_uint(f);
  u += 0x7fffu + ((u >> 16) & 1u);
  return (unsigned short)(u >> 16);
}
__device__ __forceinline__ float bflo(unsigned int u) { return __uint_as_float(u << 16); }
__device__ __forceinline__ float bfhi(unsigned int u) { return __uint_as_float(u & 0xffff0000u); }
__device__ __forceinline__ unsigned int packbf2(float a, float b) {
  return (unsigned int)f2bf(a) | ((unsigned int)f2bf(b) << 16);
}

// fp8 e4m3 (OCP) helpers — HW converts, RNE
__device__ __forceinline__ void unpack_fp8x8(float* o, uint2 u) {
  f32x2 p;
  p = __builtin_amdgcn_cvt_pk_f32_fp8(u.x, false); o[0] = p[0]; o[1] = p[1];
  p = __builtin_amdgcn_cvt_pk_f32_fp8(u.x, true);  o[2] = p[0]; o[3] = p[1];
  p = __builtin_amdgcn_cvt_pk_f32_fp8(u.y, false); o[4] = p[0]; o[5] = p[1];
  p = __builtin_amdgcn_cvt_pk_f32_fp8(u.y, true);  o[6] = p[0]; o[7] = p[1];
}
__device__ __forceinline__ void acc8_fp8(float* a, uint2 u) {
  f32x2 p;
  p = __builtin_amdgcn_cvt_pk_f32_fp8(u.x, false); a[0] += p[0]; a[1] += p[1];
  p = __builtin_amdgcn_cvt_pk_f32_fp8(u.x, true);  a[2] += p[0]; a[3] += p[1];
  p = __builtin_amdgcn_cvt_pk_f32_fp8(u.y, false); a[4] += p[0]; a[5] += p[1];
  p = __builtin_amdgcn_cvt_pk_f32_fp8(u.y, true);  a[6] += p[0]; a[7] += p[1];
}
__device__ __forceinline__ uint2 pack_fp8x8(const float* r) {
  int w0 = 0, w1 = 0;
  w0 = __builtin_amdgcn_cvt_pk_fp8_f32(r[0], r[1], w0, false);
  w0 = __builtin_amdgcn_cvt_pk_fp8_f32(r[2], r[3], w0, true);
  w1 = __builtin_amdgcn_cvt_pk_fp8_f32(r[4], r[5], w1, false);
  w1 = __builtin_amdgcn_cvt_pk_fp8_f32(r[6], r[7], w1, true);
  return make_uint2((unsigned)w0, (unsigned)w1);
}

// ---------------- CSR build: histogram ----------------
__global__ __launch_bounds__(256) void k_hist(const int* __restrict__ rows, const int* __restrict__ cols,
                                              int* __restrict__ rcnt, int* __restrict__ ccnt) {
  int i = blockIdx.x * 256 + threadIdx.x;
  if (i < NNZ) {
    atomicAdd(&rcnt[rows[i]], 1);
    atomicAdd(&ccnt[cols[i]], 1);
  }
}

__global__ __launch_bounds__(256) void k_invdeg(const int* __restrict__ rcnt, float* __restrict__ invdeg) {
  int v = blockIdx.x * 256 + threadIdx.x;
  if (v < N_V) {
    int n = rcnt[v];
    invdeg[v] = 1.f / (float)(n > 0 ? n : 1);
  }
}

__global__ __launch_bounds__(256) void k_scan_blk(const int* __restrict__ cnt, int n,
                                                  int* __restrict__ off, int* __restrict__ bsum) {
  __shared__ int s[256];
  int t = threadIdx.x;
  int base = blockIdx.x * 1024 + t * 4;
  int v0 = (base + 0 < n) ? cnt[base + 0] : 0;
  int v1 = (base + 1 < n) ? cnt[base + 1] : 0;
  int v2 = (base + 2 < n) ? cnt[base + 2] : 0;
  int v3 = (base + 3 < n) ? cnt[base + 3] : 0;
  int sum = v0 + v1 + v2 + v3;
  s[t] = sum;
  __syncthreads();
  for (int o = 1; o < 256; o <<= 1) {
    int x = (t >= o) ? s[t - o] : 0;
    __syncthreads();
    s[t] += x;
    __syncthreads();
  }
  int excl = s[t] - sum;
  if (base + 0 < n) off[base + 0] = excl;
  if (base + 1 < n) off[base + 1] = excl + v0;
  if (base + 2 < n) off[base + 2] = excl + v0 + v1;
  if (base + 3 < n) off[base + 3] = excl + v0 + v1 + v2;
  if (t == 255) bsum[blockIdx.x] = s[255];
}

__global__ __launch_bounds__(256) void k_scan_top(int* __restrict__ bsum, int nb) {
  __shared__ int s[256];
  int t = threadIdx.x;
  int v = (t < nb) ? bsum[t] : 0;
  s[t] = v;
  __syncthreads();
  for (int o = 1; o < 256; o <<= 1) {
    int x = (t >= o) ? s[t - o] : 0;
    __syncthreads();
    s[t] += x;
    __syncthreads();
  }
  if (t < nb) bsum[t] = s[t] - v;
}

__global__ __launch_bounds__(256) void k_scan_fix(int* __restrict__ off, const int* __restrict__ bsum,
                                                  int n, int* __restrict__ cur) {
  int t = threadIdx.x;
  int add = bsum[blockIdx.x];
  int base = blockIdx.x * 1024 + t * 4;
#pragma unroll
  for (int j = 0; j < 4; j++) {
    int idx = base + j;
    if (idx < n) { int v = off[idx] + add; off[idx] = v; cur[idx] = v; }
  }
  if (blockIdx.x == 0 && t == 0) off[n] = NNZ;
}

__global__ __launch_bounds__(256) void k_binit(const int* __restrict__ roff, const int* __restrict__ coff,
                                               int* __restrict__ gcurR, int* __restrict__ gcurC) {
  int t = threadIdx.x;
  if (t < 196) {
    gcurR[t] = roff[t << 9];
    gcurC[t] = coff[t << 10];
  }
}

// ---------------- binning pass ----------------
__global__ __launch_bounds__(256) void k_bin(const int* __restrict__ keys, const int* __restrict__ vals,
                                             int shift, int nb, int* __restrict__ gcur,
                                             uint2* __restrict__ binned) {
  __shared__ int bcnt[256], bsc[256], bex[256], gb[256];
  __shared__ uint2 recs[4096];
  __shared__ unsigned char bid[4096];
  int t = threadIdx.x;
  bcnt[t] = 0;
  __syncthreads();
  int base = blockIdx.x * 4096;
  int k_[16], v_[16], lp[16];
  short bb[16];
#pragma unroll
  for (int u = 0; u < 16; u++) {
    int i = base + u * 256 + t;
    if (i < NNZ) {
      k_[u] = keys[i]; v_[u] = vals[i];
      int b = k_[u] >> shift;
      bb[u] = (short)b;
      lp[u] = atomicAdd(&bcnt[b], 1);
    } else bb[u] = -1;
  }
  __syncthreads();
  bsc[t] = bcnt[t];
  __syncthreads();
  for (int o = 1; o < 256; o <<= 1) {
    int x = (t >= o) ? bsc[t - o] : 0;
    __syncthreads();
    bsc[t] += x;
    __syncthreads();
  }
  bex[t] = bsc[t] - bcnt[t];
  __syncthreads();
#pragma unroll
  for (int u = 0; u < 16; u++) {
    if (bb[u] >= 0) {
      int p = bex[bb[u]] + lp[u];
      recs[p] = make_uint2((unsigned)k_[u], (unsigned)v_[u]);
      bid[p] = (unsigned char)bb[u];
    }
  }
  if (t < nb && bcnt[t] > 0) gb[t] = atomicAdd(&gcur[t], bcnt[t]);
  __syncthreads();
  int total = bsc[255];
  for (int p = t; p < total; p += 256) {
    int b = bid[p];
    binned[gb[b] + (p - bex[b])] = recs[p];
  }
}

// ---------------- fine pass ----------------
__global__ __launch_bounds__(256) void k_fine(const uint2* __restrict__ binned, const int* __restrict__ off,
                                              int* __restrict__ idx, int* __restrict__ gcurFB,
                                              int shift, int n_keys) {
  __shared__ int cur[1024];
  __shared__ int vals[6144];
  int t = threadIdx.x;
  int kbase = blockIdx.x << shift;
  int kend = kbase + (1 << shift);
  if (kend > n_keys) kend = n_keys;
  int lo = off[kbase], hi = off[kend];
  int cnt = hi - lo;
  for (int r = t; r < kend - kbase; r += 256) cur[r] = off[kbase + r] - lo;
  __syncthreads();
  if (cnt <= 6144) {
    for (int p = t; p < cnt; p += 256) {
      uint2 rec = binned[lo + p];
      int pos = atomicAdd(&cur[(int)rec.x - kbase], 1);
      vals[pos] = (int)rec.y;
    }
    __syncthreads();
    for (int p = t; p < cnt; p += 256) idx[lo + p] = vals[p];
  } else {
    for (int p = t; p < cnt; p += 256) {
      uint2 rec = binned[lo + p];
      int pos = atomicAdd(&gcurFB[rec.x], 1);
      idx[pos] = (int)rec.y;
    }
  }
}

// ---------------- w_j = sum invdeg;  Q' = sum w_j*deg_j ----------------
__global__ __launch_bounds__(256) void k_wsum(const int* __restrict__ coff, const int* __restrict__ cidx,
                                              const float* __restrict__ invdeg,
                                              float* __restrict__ w, float* __restrict__ qsum) {
  __shared__ float red[256];
  int t = threadIdx.x;
  int j = blockIdx.x * 256 + t;
  float q = 0.f;
  if (j < N_E) {
    int o0 = coff[j], n = coff[j + 1] - o0;
    float wj = 0.f;
    for (int s = 0; s < n; s++) wj += invdeg[cidx[o0 + s]];
    w[j] = wj;
    q = wj * (float)n;
  }
  red[t] = q;
  __syncthreads();
  for (int o = 128; o > 0; o >>= 1) {
    if (t < o) red[t] += red[t + o];
    __syncthreads();
  }
  if (t == 0) atomicAdd(qsum, red[0]);
}

// ---------------- W_u = sum_{j in u} w_j;  S_u = sum_{j in u} n_j;  kapn += W_u ----------------
__global__ __launch_bounds__(256) void k_rsum(const int* __restrict__ roff, const int* __restrict__ ridx,
                                              const float* __restrict__ w, const int* __restrict__ ccnt,
                                              float* __restrict__ Wv, float* __restrict__ Sv,
                                              float* __restrict__ kapn) {
  __shared__ float red[256];
  int t = threadIdx.x;
  int v = blockIdx.x * 256 + t;
  float W = 0.f, S = 0.f;
  if (v < N_V) {
    int o0 = roff[v], n = roff[v + 1] - o0;
    for (int s = 0; s < n; ++s) { int j = ridx[o0 + s]; W += w[j]; S += (float)ccnt[j]; }
    Wv[v] = W; Sv[v] = S;
  }
  red[t] = W;
  __syncthreads();
  for (int o = 128; o > 0; o >>= 1) {
    if (t < o) red[t] += red[t + o];
    __syncthreads();
  }
  if (t == 0) atomicAdd(kapn, red[0]);
}

// ---------------- fused input weight ----------------
__global__ __launch_bounds__(128) void k_fusew(const float* __restrict__ W0, const float* __restrict__ b0,
                                               const float* __restrict__ Wl0, const float* __restrict__ bl0,
                                               float* __restrict__ W0f, float* __restrict__ b0f) {
  int n = threadIdx.x;
  for (int d = 0; d < D_IN; d++) {
    float acc = 0.f;
    for (int k = 0; k < H; k++) acc += W0[d * H + k] * Wl0[k * H + n];
    W0f[d * H + n] = acc;
  }
  float accb = bl0[n];
  for (int k = 0; k < H; k++) accb += b0[k] * Wl0[k * H + n];
  b0f[n] = accb;
}

// ---------------- h1 = x0@W0f + b0f (bf16 + fp8 out, with delta-h corrections) ----------------
__global__ __launch_bounds__(256) void k_inproj(const float* __restrict__ X, const float* __restrict__ W,
                                                const float* __restrict__ b,
                                                const float* __restrict__ Wv, const float* __restrict__ Sv,
                                                unsigned short* __restrict__ outb,
                                                unsigned char* __restrict__ out8,
                                                float* __restrict__ csx, float* __restrict__ csH) {
  __shared__ float Ws[D_IN * H];
  __shared__ float Bs[H];
  __shared__ float l1[128], l2[128];
  int t = threadIdx.x;
  for (int i = t; i < D_IN * H; i += 256) Ws[i] = W[i];
  if (t < H) Bs[t] = b[t];
  if (t < 128) { l1[t] = 0.f; l2[t] = 0.f; }
  __syncthreads();
  int cg = (t & 15) * 8;
  float c1[8] = {0.f, 0.f, 0.f, 0.f, 0.f, 0.f, 0.f, 0.f};
  float c2[8] = {0.f, 0.f, 0.f, 0.f, 0.f, 0.f, 0.f, 0.f};
  for (int it = 0; it < 4; ++it) {
    int row = blockIdx.x * 64 + it * 16 + (t >> 4);
    if (row < N_V) {
      float acc[8];
#pragma unroll
      for (int j = 0; j < 8; j++) acc[j] = Bs[cg + j];
#pragma unroll
      for (int k = 0; k < D_IN; k++) {
        float xv = X[row * D_IN + k];
#pragma unroll
        for (int j = 0; j < 8; j++) acc[j] += xv * Ws[k * H + cg + j];
      }
      unsigned int pk0 = packbf2(acc[0], acc[1]);
      unsigned int pk1 = packbf2(acc[2], acc[3]);
      unsigned int pk2 = packbf2(acc[4], acc[5]);
      unsigned int pk3 = packbf2(acc[6], acc[7]);
      *(uint4*)(outb + (size_t)row * H + cg) = make_uint4(pk0, pk1, pk2, pk3);
      uint2 pk = pack_fp8x8(acc);
      *(uint2*)(out8 + (size_t)row * H + cg) = pk;
      float back[8];
      unpack_fp8x8(back, pk);
      float Wu = Wv[row], Su = Sv[row];
#pragma unroll
      for (int j = 0; j < 8; j++) {
        float d = acc[j] - back[j];
        c1[j] += Wu * d;
        c2[j] += Su * d;
      }
    }
  }
#pragma unroll
  for (int j = 0; j < 8; j++) {
    atomicAdd(&l1[cg + j], c1[j]);
    atomicAdd(&l2[cg + j], c2[j]);
  }
  __syncthreads();
  if (t < 128) { atomicAdd(&csx[t], l1[t]); atomicAdd(&csH[t], l2[t]); }
}

// ---------------- pass 1: e1 = B^T h1 (fp8 gathers, fp8 out, delta-e corrections) ----------------
__global__ __launch_bounds__(256) void k_epass(const unsigned char* __restrict__ h8,
                                               const int* __restrict__ coff, const int* __restrict__ cidx,
                                               const float* __restrict__ w,
                                               unsigned char* __restrict__ e8,
                                               float* __restrict__ csx, float* __restrict__ csH) {
  __shared__ float cacc1[128], cacc2[128];
  int t = threadIdx.x, lane = t & 63;
  int eg = lane >> 4, sl = lane & 15;
  if (t < 128) { cacc1[t] = 0.f; cacc2[t] = 0.f; }
  __syncthreads();
  int gw = blockIdx.x * 4 + (t >> 6);
  int nw = gridDim.x * 4;
  float A1[8] = {0.f, 0.f, 0.f, 0.f, 0.f, 0.f, 0.f, 0.f};
  float A2[8] = {0.f, 0.f, 0.f, 0.f, 0.f, 0.f, 0.f, 0.f};
  const int NB = (N_E + 3) >> 2;
  for (int b = gw; b < NB; b += nw) {
    int j = b * 4 + eg;
    bool jv = j < N_E;
    int o0 = 0, n = 0;
    float wj = 0.f;
    if (jv) { o0 = coff[j]; n = coff[j + 1] - o0; wj = w[j]; }
    float a[8] = {0.f, 0.f, 0.f, 0.f, 0.f, 0.f, 0.f, 0.f};
    int s = 0;
    for (; s + 4 <= n; s += 4) {
      int v0 = cidx[o0 + s], v1 = cidx[o0 + s + 1], v2 = cidx[o0 + s + 2], v3 = cidx[o0 + s + 3];
      uint2 u0 = *(const uint2*)(h8 + (size_t)v0 * H + sl * 8);
      uint2 u1 = *(const uint2*)(h8 + (size_t)v1 * H + sl * 8);
      uint2 u2 = *(const uint2*)(h8 + (size_t)v2 * H + sl * 8);
      uint2 u3 = *(const uint2*)(h8 + (size_t)v3 * H + sl * 8);
      acc8_fp8(a, u0); acc8_fp8(a, u1); acc8_fp8(a, u2); acc8_fp8(a, u3);
    }
    for (; s < n; ++s) {
      int v = cidx[o0 + s];
      uint2 u = *(const uint2*)(h8 + (size_t)v * H + sl * 8);
      acc8_fp8(a, u);
    }
    if (jv) {
      uint2 pk = pack_fp8x8(a);
      *(uint2*)(e8 + (size_t)j * H + sl * 8) = pk;
      float back[8];
      unpack_fp8x8(back, pk);
      float fn = (float)n;
#pragma unroll
      for (int k = 0; k < 8; k++) {
        float d = a[k] - back[k];
        A1[k] += wj * d;
        A2[k] += fn * d;
      }
    }
  }
#pragma unroll
  for (int k = 0; k < 8; k++) {
    float v1 = A1[k], v2 = A2[k];
    v1 += __shfl_xor(v1, 16); v1 += __shfl_xor(v1, 32);
    v2 += __shfl_xor(v2, 16); v2 += __shfl_xor(v2, 32);
    if (eg == 0) { atomicAdd(&cacc1[sl * 8 + k], v1); atomicAdd(&cacc2[sl * 8 + k], v2); }
  }
  __syncthreads();
  if (t < 128) { atomicAdd(&csx[t], cacc1[t]); atomicAdd(&csH[t], cacc2[t]); }
}

// ---------------- pass 2: a2 = h1 + D^-1 B e1; fp8 out; csx main; delta-a corrections ----------------
__global__ __launch_bounds__(256) void k_mpass(const unsigned char* __restrict__ e8,
                                               const int* __restrict__ roff, const int* __restrict__ ridx,
                                               const unsigned short* __restrict__ hb,
                                               const float* __restrict__ Wv,
                                               unsigned char* __restrict__ a8,
                                               float* __restrict__ csx, float* __restrict__ csE,
                                               float* __restrict__ csW) {
  __shared__ float cacc0[128], cacc1[128], cacc2[128];
  int t = threadIdx.x, lane = t & 63;
  int eg = lane >> 4, sl = lane & 15;
  if (t < 128) { cacc0[t] = 0.f; cacc1[t] = 0.f; cacc2[t] = 0.f; }
  __syncthreads();
  int gw = blockIdx.x * 4 + (t >> 6);
  int nw = gridDim.x * 4;
  float cs[8] = {0.f, 0.f, 0.f, 0.f, 0.f, 0.f, 0.f, 0.f};
  float cE[8] = {0.f, 0.f, 0.f, 0.f, 0.f, 0.f, 0.f, 0.f};
  float cW[8] = {0.f, 0.f, 0.f, 0.f, 0.f, 0.f, 0.f, 0.f};
  const int NB = (N_V + 3) >> 2;
  for (int b = gw; b < NB; b += nw) {
    int v = b * 4 + eg;
    bool vv = v < N_V;
    int o0 = 0, n = 0;
    if (vv) { o0 = roff[v]; n = roff[v + 1] - o0; }
    float a[8] = {0.f, 0.f, 0.f, 0.f, 0.f, 0.f, 0.f, 0.f};
    int s = 0;
    for (; s + 4 <= n; s += 4) {
      int j0 = ridx[o0 + s], j1 = ridx[o0 + s + 1], j2 = ridx[o0 + s + 2], j3 = ridx[o0 + s + 3];
      uint2 u0 = *(const uint2*)(e8 + (size_t)j0 * H + sl * 8);
      uint2 u1 = *(const uint2*)(e8 + (size_t)j1 * H + sl * 8);
      uint2 u2 = *(const uint2*)(e8 + (size_t)j2 * H + sl * 8);
      uint2 u3 = *(const uint2*)(e8 + (size_t)j3 * H + sl * 8);
      acc8_fp8(a, u0); acc8_fp8(a, u1); acc8_fp8(a, u2); acc8_fp8(a, u3);
    }
    for (; s < n; ++s) {
      int j = ridx[o0 + s];
      uint2 u = *(const uint2*)(e8 + (size_t)j * H + sl * 8);
      acc8_fp8(a, u);
    }
    if (vv) {
      float inv = (n > 0) ? (1.f / (float)n) : 1.f;
      uint4 uh = *(const uint4*)(hb + (size_t)v * H + sl * 8);
      float r[8];
      r[0] = bflo(uh.x) + a[0] * inv; r[1] = bfhi(uh.x) + a[1] * inv;
      r[2] = bflo(uh.y) + a[2] * inv; r[3] = bfhi(uh.y) + a[3] * inv;
      r[4] = bflo(uh.z) + a[4] * inv; r[5] = bfhi(uh.z) + a[5] * inv;
      r[6] = bflo(uh.w) + a[6] * inv; r[7] = bfhi(uh.w) + a[7] * inv;
      uint2 pk = pack_fp8x8(r);
      *(uint2*)(a8 + (size_t)v * H + sl * 8) = pk;
      float back[8];
      unpack_fp8x8(back, pk);
      float fn = (float)n;
      float Wvv = Wv[v];
#pragma unroll
      for (int k = 0; k < 8; k++) {
        float d = r[k] - back[k];
        cs[k] += r[k];
        cE[k] += fn * d;
        cW[k] += Wvv * d;
      }
    }
  }
#pragma unroll
  for (int k = 0; k < 8; k++) {
    float v0 = cs[k], v1 = cE[k], v2 = cW[k];
    v0 += __shfl_xor(v0, 16); v0 += __shfl_xor(v0, 32);
    v1 += __shfl_xor(v1, 16); v1 += __shfl_xor(v1, 32);
    v2 += __shfl_xor(v2, 16); v2 += __shfl_xor(v2, 32);
    if (eg == 0) {
      atomicAdd(&cacc0[sl * 8 + k], v0);
      atomicAdd(&cacc1[sl * 8 + k], v1);
      atomicAdd(&cacc2[sl * 8 + k], v2);
    }
  }
  __syncthreads();
  if (t < 128) {
    atomicAdd(&csx[t], cacc0[t]);
    atomicAdd(&csE[t], cacc1[t]);
    atomicAdd(&csW[t], cacc2[t]);
  }
}

// ---------------- pass 3: Ea rows (not stored): csE += row, csW += w_j * row ----------------
__global__ __launch_bounds__(256) void k_efin(const unsigned char* __restrict__ a8,
                                              const int* __restrict__ coff, const int* __restrict__ cidx,
                                              const float* __restrict__ w,
                                              float* __restrict__ csE, float* __restrict__ csW) {
  __shared__ float caccE[128], caccW[128];
  int t = threadIdx.x, lane = t & 63;
  int eg = lane >> 4, sl = lane & 15;
  if (t < 128) { caccE[t] = 0.f; caccW[t] = 0.f; }
  __syncthreads();
  int gw = blockIdx.x * 4 + (t >> 6);
  int nw = gridDim.x * 4;
  float ce[8] = {0.f, 0.f, 0.f, 0.f, 0.f, 0.f, 0.f, 0.f};
  float cw[8] = {0.f, 0.f, 0.f, 0.f, 0.f, 0.f, 0.f, 0.f};
  const int NB = (N_E + 3) >> 2;
  for (int b = gw; b < NB; b += nw) {
    int j = b * 4 + eg;
    bool jv = j < N_E;
    int o0 = 0, n = 0;
    float wj = 0.f;
    if (jv) { o0 = coff[j]; n = coff[j + 1] - o0; wj = w[j]; }
    float a[8] = {0.f, 0.f, 0.f, 0.f, 0.f, 0.f, 0.f, 0.f};
    int s = 0;
    for (; s + 4 <= n; s += 4) {
      int v0 = cidx[o0 + s], v1 = cidx[o0 + s + 1], v2 = cidx[o0 + s + 2], v3 = cidx[o0 + s + 3];
      uint2 u0 = *(const uint2*)(a8 + (size_t)v0 * H + sl * 8);
      uint2 u1 = *(const uint2*)(a8 + (size_t)v1 * H + sl * 8);
      uint2 u2 = *(const uint2*)(a8 + (size_t)v2 * H + sl * 8);
      uint2 u3 = *(const uint2*)(a8 + (size_t)v3 * H + sl * 8);
      acc8_fp8(a, u0); acc8_fp8(a, u1); acc8_fp8(a, u2); acc8_fp8(a, u3);
    }
    for (; s < n; ++s) {
      int v = cidx[o0 + s];
      uint2 u = *(const uint2*)(a8 + (size_t)v * H + sl * 8);
      acc8_fp8(a, u);
    }
    if (jv) {
#pragma unroll
      for (int k = 0; k < 8; k++) { ce[k] += a[k]; cw[k] += wj * a[k]; }
    }
  }
#pragma unroll
  for (int k = 0; k < 8; k++) {
    float ve = ce[k], vw = cw[k];
    ve += __shfl_xor(ve, 16); ve += __shfl_xor(ve, 32);
    vw += __shfl_xor(vw, 16); vw += __shfl_xor(vw, 32);
    if (eg == 0) { atomicAdd(&caccE[sl * 8 + k], ve); atomicAdd(&caccW[sl * 8 + k], vw); }
  }
  __syncthreads();
  if (t < 128) { atomicAdd(&csE[t], caccE[t]); atomicAdd(&csW[t], caccW[t]); }
}

// ---------------- final ----------------
__global__ __launch_bounds__(128) void k_final(const float* __restrict__ csx, const float* __restrict__ csW,
                                               const float* __restrict__ csE, const float* __restrict__ csH,
                                               const float* __restrict__ qsum, const float* __restrict__ kapn,
                                               const float* __restrict__ Wl1, const float* __restrict__ bl1,
                                               const float* __restrict__ Wo0, const float* __restrict__ bo0,
                                               const float* __restrict__ Wo1, const float* __restrict__ bo1,
                                               float* __restrict__ out) {
  __shared__ float red[128];
  int t = threadIdx.x;
  float kap = kapn[0] * (1.f / (float)NNZ);
  float sx = 0.f, se = 0.f;
  for (int k = 0; k < H; k++) {
    float wv = Wl1[k * H + t];
    float csWt = csW[k] + kap * csH[k];
    float csEt = csE[k] + csH[k];
    sx += (csx[k] + csWt) * wv;
    se += csEt * wv;
  }
  float Q = qsum[0];
  sx += ((float)N_V + Q) * bl1[t];
  se += (float)NNZ * bl1[t];
  float v = sx * (1.0f / (float)N_V) * Wo0[t] + se * (1.0f / (float)N_E) * Wo1[t];
  red[t] = v;
  __syncthreads();
  for (int o = 64; o > 0; o >>= 1) {
    if (t < o) red[t] += red[t + o];
    __syncthreads();
  }
  if (t == 0) out[0] = red[0] + bo0[0] + bo1[0];
}

extern "C" void kernel_launch(void* const* d_in, const int* in_sizes, int n_in,
                              void* d_out, int out_size, void* d_ws, size_t ws_size,
                              hipStream_t stream) {
  const float* x0in = (const float*)d_in[0];
  const int* rows   = (const int*)d_in[2];
  const int* cols   = (const int*)d_in[3];
  const float* W0   = (const float*)d_in[4];
  const float* b0   = (const float*)d_in[5];
  const float* Wl0  = (const float*)d_in[8];
  const float* bl0  = (const float*)d_in[9];
  const float* Wl1  = (const float*)d_in[10];
  const float* bl1  = (const float*)d_in[11];
  const float* Wo0  = (const float*)d_in[12];
  const float* bo0  = (const float*)d_in[13];
  const float* Wo1  = (const float*)d_in[14];
  const float* bo1  = (const float*)d_in[15];
  float* out = (float*)d_out;
  char* ws = (char*)d_ws;

  // workspace layout (zero region first)
  int*   rcnt  = (int*)(ws + 0);              //   400000
  int*   ccnt  = (int*)(ws + 400000);         //   800000 -> 1200000
  float* csx   = (float*)(ws + 1200000);      //      512
  float* csE   = (float*)(ws + 1200512);      //      512
  float* csW   = (float*)(ws + 1201024);      //      512
  float* csH   = (float*)(ws + 1201536);      //      512
  float* qsum  = (float*)(ws + 1202048);      //        4
  float* kapn  = (float*)(ws + 1202052);      //        4  -> zero [0, 1202056)
  int*   roff  = (int*)(ws + 1202176);        //   400004
  int*   coff  = (int*)(ws + 1602304);        //   800004
  int*   rcur  = (int*)(ws + 2402432);        //   400000
  int*   ccur  = (int*)(ws + 2802432);        //   800000
  int*   ridx  = (int*)(ws + 3602432);        //  3200000
  int*   cidx  = (int*)(ws + 6802432);        //  3200000
  int*   bsR   = (int*)(ws + 10002432);       //     1024
  int*   bsC   = (int*)(ws + 10003456);       //     1024
  int*   gcurR = (int*)(ws + 10004480);       //     1024
  int*   gcurC = (int*)(ws + 10005504);       //     1024
  float* invdg = (float*)(ws + 10006528);     //   400000
  float* wbuf  = (float*)(ws + 10406528);     //   800000
  float* Wv    = (float*)(ws + 11206528);     //   400000
  float* Sv    = (float*)(ws + 11606528);     //   400000
  float* W0f   = (float*)(ws + 12006528);     //     7168
  float* b0f   = (float*)(ws + 12013696);     //      512
  unsigned short* hb = (unsigned short*)(ws + 12014208);  // bf16 h1: 25600000 -> 37614208
  unsigned char*  h8 = (unsigned char*)(ws + 37614208);   // fp8 h1:  12800000 -> 50414208
  unsigned char*  e8 = (unsigned char*)(ws + 50414208);   // fp8 e1:  25600000 -> 76014208
  unsigned char*  a8 = (unsigned char*)(ws + 76014208);   // fp8 a2:  12800000 -> 88814208
  // binned temps alias e8 region (consumed by k_fine before k_epass writes e8)
  uint2* binnedR = (uint2*)(ws + 50414208);               // 6400000
  uint2* binnedC = (uint2*)(ws + 56814208);               // 6400000
  // total: 88814208 B

  hipMemsetAsync(ws, 0, 1202056, stream);
  k_hist<<<dim3((NNZ + 255) / 256), dim3(256), 0, stream>>>(rows, cols, rcnt, ccnt);
  k_invdeg<<<dim3((N_V + 255) / 256), dim3(256), 0, stream>>>(rcnt, invdg);
  k_scan_blk<<<dim3(98),  dim3(256), 0, stream>>>(rcnt, N_V, roff, bsR);
  k_scan_blk<<<dim3(196), dim3(256), 0, stream>>>(ccnt, N_E, coff, bsC);
  k_scan_top<<<dim3(1), dim3(256), 0, stream>>>(bsR, 98);
  k_scan_top<<<dim3(1), dim3(256), 0, stream>>>(bsC, 196);
  k_scan_fix<<<dim3(98),  dim3(256), 0, stream>>>(roff, bsR, N_V, rcur);
  k_scan_fix<<<dim3(196), dim3(256), 0, stream>>>(coff, bsC, N_E, ccur);
  k_binit<<<dim3(1), dim3(256), 0, stream>>>(roff, coff, gcurR, gcurC);
  k_bin<<<dim3(196), dim3(256), 0, stream>>>(rows, cols, 9, 196, gcurR, binnedR);
  k_bin<<<dim3(196), dim3(256), 0, stream>>>(cols, rows, 10, 196, gcurC, binnedC);
  k_fine<<<dim3(196), dim3(256), 0, stream>>>(binnedR, roff, ridx, rcur, 9, N_V);
  k_fine<<<dim3(196), dim3(256), 0, stream>>>(binnedC, coff, cidx, ccur, 10, N_E);
  k_wsum<<<dim3((N_E + 255) / 256), dim3(256), 0, stream>>>(coff, cidx, invdg, wbuf, qsum);
  k_rsum<<<dim3((N_V + 255) / 256), dim3(256), 0, stream>>>(roff, ridx, wbuf, ccnt, Wv, Sv, kapn);

  k_fusew<<<dim3(1), dim3(128), 0, stream>>>(W0, b0, Wl0, bl0, W0f, b0f);
  k_inproj<<<dim3((N_V + 63) / 64), dim3(256), 0, stream>>>(x0in, W0f, b0f, Wv, Sv, hb, h8, csx, csH);
  k_epass<<<dim3(2048), dim3(256), 0, stream>>>(h8, coff, cidx, wbuf, e8, csx, csH);
  k_mpass<<<dim3(2048), dim3(256), 0, stream>>>(e8, roff, ridx, hb, Wv, a8, csx, csE, csW);
  k_efin<<<dim3(2048), dim3(256), 0, stream>>>(a8, coff, cidx, wbuf, csE, csW);
  k_final<<<dim3(1), dim3(128), 0, stream>>>(csx, csW, csE, csH, qsum, kapn, Wl1, bl1, Wo0, bo0, Wo1, bo1, out);
}

// Round 7
// 555.527 us; speedup vs baseline: 1.0849x; 1.0849x over previous
//
#include <hip/hip_runtime.h>
#include <stdint.h>

#define N_V 100000
#define N_E 200000
#define NNZ 800000
#define D_IN 14
#define H 128

// ---------------- histogram: rcnt (vertex deg), ccnt (edge size) ----------------
__global__ __launch_bounds__(256) void k_hist(const int* __restrict__ rows, const int* __restrict__ cols,
                                              int* __restrict__ rcnt, int* __restrict__ ccnt) {
  int i = blockIdx.x * 256 + threadIdx.x;
  if (i < NNZ) {
    atomicAdd(&rcnt[rows[i]], 1);
    atomicAdd(&ccnt[cols[i]], 1);
  }
}

// ---------------- COO pass A: w[c] += 1/deg[r] ----------------
__global__ __launch_bounds__(256) void k_cooA(const int* __restrict__ rows, const int* __restrict__ cols,
                                              const int* __restrict__ rcnt, float* __restrict__ w) {
  int i = (blockIdx.x * 256 + threadIdx.x) * 4;
  if (i < NNZ) {
    int4 r = *(const int4*)(rows + i);
    int4 c = *(const int4*)(cols + i);
    atomicAdd(&w[c.x], 1.f / (float)max(rcnt[r.x], 1));
    atomicAdd(&w[c.y], 1.f / (float)max(rcnt[r.y], 1));
    atomicAdd(&w[c.z], 1.f / (float)max(rcnt[r.z], 1));
    atomicAdd(&w[c.w], 1.f / (float)max(rcnt[r.w], 1));
  }
}

// ---------------- COO pass B: Wv[r] += w[c]; Sv[r] += n[c]; Q += w[c] ----------------
__global__ __launch_bounds__(256) void k_cooB(const int* __restrict__ rows, const int* __restrict__ cols,
                                              const float* __restrict__ w, const int* __restrict__ ccnt,
                                              float* __restrict__ Wv, float* __restrict__ Sv,
                                              float* __restrict__ qsum) {
  __shared__ float red[256];
  int t = threadIdx.x;
  int i = (blockIdx.x * 256 + t) * 4;
  float q = 0.f;
  if (i < NNZ) {
    int4 r = *(const int4*)(rows + i);
    int4 c = *(const int4*)(cols + i);
    float w0 = w[c.x], w1 = w[c.y], w2 = w[c.z], w3 = w[c.w];
    atomicAdd(&Wv[r.x], w0); atomicAdd(&Wv[r.y], w1);
    atomicAdd(&Wv[r.z], w2); atomicAdd(&Wv[r.w], w3);
    atomicAdd(&Sv[r.x], (float)ccnt[c.x]); atomicAdd(&Sv[r.y], (float)ccnt[c.y]);
    atomicAdd(&Sv[r.z], (float)ccnt[c.z]); atomicAdd(&Sv[r.w], (float)ccnt[c.w]);
    q = (w0 + w1) + (w2 + w3);
  }
  red[t] = q;
  __syncthreads();
  for (int o = 128; o > 0; o >>= 1) {
    if (t < o) red[t] += red[t + o];
    __syncthreads();
  }
  if (t == 0) atomicAdd(qsum, red[0]);
}

// ---------------- COO pass C: z[c] += Wv[r]/deg[r] ----------------
__global__ __launch_bounds__(256) void k_cooC(const int* __restrict__ rows, const int* __restrict__ cols,
                                              const int* __restrict__ rcnt, const float* __restrict__ Wv,
                                              float* __restrict__ z) {
  int i = (blockIdx.x * 256 + threadIdx.x) * 4;
  if (i < NNZ) {
    int4 r = *(const int4*)(rows + i);
    int4 c = *(const int4*)(cols + i);
    atomicAdd(&z[c.x], Wv[r.x] / (float)max(rcnt[r.x], 1));
    atomicAdd(&z[c.y], Wv[r.y] / (float)max(rcnt[r.y], 1));
    atomicAdd(&z[c.z], Wv[r.z] / (float)max(rcnt[r.z], 1));
    atomicAdd(&z[c.w], Wv[r.w] / (float)max(rcnt[r.w], 1));
  }
}

// ---------------- COO pass D: Z2[r] += z[c] ----------------
__global__ __launch_bounds__(256) void k_cooD(const int* __restrict__ rows, const int* __restrict__ cols,
                                              const float* __restrict__ z, float* __restrict__ Z2) {
  int i = (blockIdx.x * 256 + threadIdx.x) * 4;
  if (i < NNZ) {
    int4 r = *(const int4*)(rows + i);
    int4 c = *(const int4*)(cols + i);
    atomicAdd(&Z2[r.x], z[c.x]);
    atomicAdd(&Z2[r.y], z[c.y]);
    atomicAdd(&Z2[r.z], z[c.z]);
    atomicAdd(&Z2[r.w], z[c.w]);
  }
}

// ---------------- fused input weight: W0f = W0 @ Wl0, b0f = b0 @ Wl0 + bl0 ----------------
__global__ __launch_bounds__(128) void k_fusew(const float* __restrict__ W0, const float* __restrict__ b0,
                                               const float* __restrict__ Wl0, const float* __restrict__ bl0,
                                               float* __restrict__ W0f, float* __restrict__ b0f) {
  int n = threadIdx.x;
  for (int d = 0; d < D_IN; d++) {
    float acc = 0.f;
    for (int k = 0; k < H; k++) acc += W0[d * H + k] * Wl0[k * H + n];
    W0f[d * H + n] = acc;
  }
  float accb = bl0[n];
  for (int k = 0; k < H; k++) accb += b0[k] * Wl0[k * H + n];
  b0f[n] = accb;
}

// ---------------- dense pass: h1_v in-register; accumulate 4 weighted colsums ----------------
// partial[blk][0..127]=colsum(h1), [128..255]=sum Wv*h, [256..383]=sum (rdeg+Sv)*h, [384..511]=sum (Wv+Z2)*h
__global__ __launch_bounds__(256) void k_dense(const float* __restrict__ X, const float* __restrict__ W0f,
                                               const float* __restrict__ b0f,
                                               const int* __restrict__ rcnt, const float* __restrict__ Wv,
                                               const float* __restrict__ Sv, const float* __restrict__ Z2,
                                               float* __restrict__ partial) {
  __shared__ float Ws[D_IN * H];
  __shared__ float Bs[H];
  __shared__ float l0[128], l1[128], l2[128], l3[128];
  int t = threadIdx.x;
  for (int i = t; i < D_IN * H; i += 256) Ws[i] = W0f[i];
  if (t < H) Bs[t] = b0f[t];
  if (t < 128) { l0[t] = 0.f; l1[t] = 0.f; l2[t] = 0.f; l3[t] = 0.f; }
  __syncthreads();
  int lane = t & 63, eg = lane >> 4, sl = lane & 15;
  int cg = sl * 8;
  float c0[8] = {0,0,0,0,0,0,0,0}, c1[8] = {0,0,0,0,0,0,0,0};
  float c2[8] = {0,0,0,0,0,0,0,0}, c3[8] = {0,0,0,0,0,0,0,0};
  for (int it = 0; it < 16; ++it) {
    int row = blockIdx.x * 256 + it * 16 + (t >> 4);
    if (row < N_V) {
      float acc[8];
#pragma unroll
      for (int j = 0; j < 8; j++) acc[j] = Bs[cg + j];
#pragma unroll
      for (int k = 0; k < D_IN; k++) {
        float xv = X[row * D_IN + k];
#pragma unroll
        for (int j = 0; j < 8; j++) acc[j] += xv * Ws[k * H + cg + j];
      }
      float g1 = Wv[row];
      float g2 = (float)rcnt[row] + Sv[row];
      float g3 = g1 + Z2[row];
#pragma unroll
      for (int j = 0; j < 8; j++) {
        float a = acc[j];
        c0[j] += a; c1[j] += g1 * a; c2[j] += g2 * a; c3[j] += g3 * a;
      }
    }
  }
#pragma unroll
  for (int j = 0; j < 8; j++) {
    float v0 = c0[j], v1 = c1[j], v2 = c2[j], v3 = c3[j];
    v0 += __shfl_xor(v0, 16); v0 += __shfl_xor(v0, 32);
    v1 += __shfl_xor(v1, 16); v1 += __shfl_xor(v1, 32);
    v2 += __shfl_xor(v2, 16); v2 += __shfl_xor(v2, 32);
    v3 += __shfl_xor(v3, 16); v3 += __shfl_xor(v3, 32);
    if (eg == 0) {
      atomicAdd(&l0[cg + j], v0);
      atomicAdd(&l1[cg + j], v1);
      atomicAdd(&l2[cg + j], v2);
      atomicAdd(&l3[cg + j], v3);
    }
  }
  __syncthreads();
  if (t < 128) {
    float* p = partial + (size_t)blockIdx.x * 512;
    p[t] = l0[t]; p[128 + t] = l1[t]; p[256 + t] = l2[t]; p[384 + t] = l3[t];
  }
}

// ---------------- final: reduce partials, push Wl1, output heads ----------------
__global__ __launch_bounds__(512) void k_final(const float* __restrict__ partial, int nblk,
                                               const float* __restrict__ qsum,
                                               const float* __restrict__ Wl1, const float* __restrict__ bl1,
                                               const float* __restrict__ Wo0, const float* __restrict__ bo0,
                                               const float* __restrict__ Wo1, const float* __restrict__ bo1,
                                               float* __restrict__ out) {
  __shared__ float cs[512];   // [0:128)=csH1, [128:256)=csA, [256:384)=csE, [384:512)=csW
  __shared__ float red[128];
  int t = threadIdx.x;
  float s = 0.f;
  for (int b = 0; b < nblk; b++) s += partial[(size_t)b * 512 + t];
  cs[t] = s;
  __syncthreads();
  if (t < 128) {
    float sx = 0.f, se = 0.f;
    for (int k = 0; k < H; k++) {
      float wv = Wl1[k * H + t];
      float csx = cs[k] + cs[128 + k];        // colsum(a2) = colsum(h1) + sum w_k e1_k
      sx += (csx + cs[384 + k]) * wv;
      se += cs[256 + k] * wv;
    }
    float Q = qsum[0];
    sx += ((float)N_V + Q) * bl1[t];
    se += (float)NNZ * bl1[t];
    red[t] = sx * (1.f / (float)N_V) * Wo0[t] + se * (1.f / (float)N_E) * Wo1[t];
  }
  __syncthreads();
  for (int o = 64; o > 0; o >>= 1) {
    if (t < o) red[t] += red[t + o];
    __syncthreads();
  }
  if (t == 0) out[0] = red[0] + bo0[0] + bo1[0];
}

extern "C" void kernel_launch(void* const* d_in, const int* in_sizes, int n_in,
                              void* d_out, int out_size, void* d_ws, size_t ws_size,
                              hipStream_t stream) {
  const float* x0in = (const float*)d_in[0];
  const int* rows   = (const int*)d_in[2];
  const int* cols   = (const int*)d_in[3];
  const float* W0   = (const float*)d_in[4];
  const float* b0   = (const float*)d_in[5];
  const float* Wl0  = (const float*)d_in[8];
  const float* bl0  = (const float*)d_in[9];
  const float* Wl1  = (const float*)d_in[10];
  const float* bl1  = (const float*)d_in[11];
  const float* Wo0  = (const float*)d_in[12];
  const float* bo0  = (const float*)d_in[13];
  const float* Wo1  = (const float*)d_in[14];
  const float* bo1  = (const float*)d_in[15];
  float* out = (float*)d_out;
  char* ws = (char*)d_ws;

  // workspace layout — [0, 4000004) zeroed each call
  int*   rcnt = (int*)(ws + 0);              //  400000
  int*   ccnt = (int*)(ws + 400000);         //  800000
  float* w    = (float*)(ws + 1200000);      //  800000  w_j = sum invdeg over members
  float* Wv   = (float*)(ws + 2000000);      //  400000  W_v = sum w_j over incident edges
  float* Sv   = (float*)(ws + 2400000);      //  400000  S_v = sum n_j over incident edges
  float* z    = (float*)(ws + 2800000);      //  800000  z_j = sum W_v/deg_v over members
  float* Z2   = (float*)(ws + 3600000);      //  400000  Z2_v = sum z_j over incident edges
  float* qsum = (float*)(ws + 4000000);      //       4  Q = sum_j w_j n_j
  float* W0f  = (float*)(ws + 4000256);      //    7168
  float* b0f  = (float*)(ws + 4007424);      //     512
  float* partial = (float*)(ws + 4007936);   //  391*512*4 = 800768 (fully overwritten)
  // total: 4808704 B

  const int NBLK = (N_V + 255) / 256;        // 391
  const int GCOO = (NNZ / 4 + 255) / 256;    // 782

  hipMemsetAsync(ws, 0, 4000004, stream);
  k_hist<<<dim3((NNZ + 255) / 256), dim3(256), 0, stream>>>(rows, cols, rcnt, ccnt);
  k_cooA<<<dim3(GCOO), dim3(256), 0, stream>>>(rows, cols, rcnt, w);
  k_cooB<<<dim3(GCOO), dim3(256), 0, stream>>>(rows, cols, w, ccnt, Wv, Sv, qsum);
  k_cooC<<<dim3(GCOO), dim3(256), 0, stream>>>(rows, cols, rcnt, Wv, z);
  k_cooD<<<dim3(GCOO), dim3(256), 0, stream>>>(rows, cols, z, Z2);
  k_fusew<<<dim3(1), dim3(128), 0, stream>>>(W0, b0, Wl0, bl0, W0f, b0f);
  k_dense<<<dim3(NBLK), dim3(256), 0, stream>>>(x0in, W0f, b0f, rcnt, Wv, Sv, Z2, partial);
  k_final<<<dim3(1), dim3(512), 0, stream>>>(partial, NBLK, qsum, Wl1, bl1, Wo0, bo0, Wo1, bo1, out);
}

// Round 8
// 447.806 us; speedup vs baseline: 1.3459x; 1.2406x over previous
//
#include <hip/hip_runtime.h>
#include <stdint.h>

#define N_V 100000
#define N_E 200000
#define NNZ 800000
#define D_IN 14
#define H 128

#define SV 100096   // padded vertex stride (×16)
#define SE 200192   // padded edge stride (×16)

// ---------------- histogram (8-way XCD-privatized) ----------------
__global__ __launch_bounds__(256) void k_hist8(const int* __restrict__ rows, const int* __restrict__ cols,
                                               int* __restrict__ rcnt8, int* __restrict__ ccnt8) {
  int i = (blockIdx.x * 256 + threadIdx.x) * 4;
  if (i < NNZ) {
    int part = blockIdx.x & 7;
    int* rc = rcnt8 + part * SV;
    int* cc = ccnt8 + part * SE;
    int4 r = *(const int4*)(rows + i);
    int4 c = *(const int4*)(cols + i);
    atomicAdd(&rc[r.x], 1); atomicAdd(&rc[r.y], 1);
    atomicAdd(&rc[r.z], 1); atomicAdd(&rc[r.w], 1);
    atomicAdd(&cc[c.x], 1); atomicAdd(&cc[c.y], 1);
    atomicAdd(&cc[c.z], 1); atomicAdd(&cc[c.w], 1);
  }
}

// ---------------- merge rcnt/ccnt -> rdegf, invdeg, cn ----------------
__global__ __launch_bounds__(256) void k_mergeRC(const int* __restrict__ rcnt8, const int* __restrict__ ccnt8,
                                                 float* __restrict__ rdegf, float* __restrict__ invdeg,
                                                 float* __restrict__ cn) {
  int i = blockIdx.x * 256 + threadIdx.x;
  if (i < N_V) {
    int s = 0;
#pragma unroll
    for (int p = 0; p < 8; p++) s += rcnt8[p * SV + i];
    rdegf[i] = (float)s;
    invdeg[i] = 1.f / (float)(s > 0 ? s : 1);
  }
  if (i < N_E) {
    int s = 0;
#pragma unroll
    for (int p = 0; p < 8; p++) s += ccnt8[p * SE + i];
    cn[i] = (float)s;
  }
}

// ---------------- COO pass A: w[c] += invdeg[r] ----------------
__global__ __launch_bounds__(256) void k_cooA8(const int* __restrict__ rows, const int* __restrict__ cols,
                                               const float* __restrict__ invdeg, float* __restrict__ w8) {
  int i = (blockIdx.x * 256 + threadIdx.x) * 4;
  if (i < NNZ) {
    float* wp = w8 + (blockIdx.x & 7) * SE;
    int4 r = *(const int4*)(rows + i);
    int4 c = *(const int4*)(cols + i);
    atomicAdd(&wp[c.x], invdeg[r.x]);
    atomicAdd(&wp[c.y], invdeg[r.y]);
    atomicAdd(&wp[c.z], invdeg[r.z]);
    atomicAdd(&wp[c.w], invdeg[r.w]);
  }
}

// ---------------- merge w -> wn=(w_j, n_j); qsum += w_j*n_j ----------------
__global__ __launch_bounds__(256) void k_mergeW(const float* __restrict__ w8, const float* __restrict__ cn,
                                                float2* __restrict__ wn, float* __restrict__ qsum) {
  __shared__ float red[256];
  int t = threadIdx.x;
  int j = blockIdx.x * 256 + t;
  float q = 0.f;
  if (j < N_E) {
    float s = 0.f;
#pragma unroll
    for (int p = 0; p < 8; p++) s += w8[p * SE + j];
    float n = cn[j];
    wn[j] = make_float2(s, n);
    q = s * n;
  }
  red[t] = q;
  __syncthreads();
  for (int o = 128; o > 0; o >>= 1) {
    if (t < o) red[t] += red[t + o];
    __syncthreads();
  }
  if (t == 0) atomicAdd(qsum, red[0]);
}

// ---------------- COO pass B: Wv[r] += w[c]; Sv[r] += n[c]  (interleaved) ----------------
__global__ __launch_bounds__(256) void k_cooB8(const int* __restrict__ rows, const int* __restrict__ cols,
                                               const float2* __restrict__ wn, float* __restrict__ WS8) {
  int i = (blockIdx.x * 256 + threadIdx.x) * 4;
  if (i < NNZ) {
    float* ws = WS8 + (blockIdx.x & 7) * SE;   // 2 floats per vertex
    int4 r = *(const int4*)(rows + i);
    int4 c = *(const int4*)(cols + i);
    float2 a = wn[c.x], b = wn[c.y], d = wn[c.z], e = wn[c.w];
    atomicAdd(&ws[2 * r.x], a.x); atomicAdd(&ws[2 * r.x + 1], a.y);
    atomicAdd(&ws[2 * r.y], b.x); atomicAdd(&ws[2 * r.y + 1], b.y);
    atomicAdd(&ws[2 * r.z], d.x); atomicAdd(&ws[2 * r.z + 1], d.y);
    atomicAdd(&ws[2 * r.w], e.x); atomicAdd(&ws[2 * r.w + 1], e.y);
  }
}

// ---------------- merge WS -> Wv, Sv, WvD ----------------
__global__ __launch_bounds__(256) void k_mergeWS(const float* __restrict__ WS8, const float* __restrict__ invdeg,
                                                 float* __restrict__ Wv, float* __restrict__ Sv,
                                                 float* __restrict__ WvD) {
  int v = blockIdx.x * 256 + threadIdx.x;
  if (v < N_V) {
    float W = 0.f, S = 0.f;
#pragma unroll
    for (int p = 0; p < 8; p++) { W += WS8[p * SE + 2 * v]; S += WS8[p * SE + 2 * v + 1]; }
    Wv[v] = W; Sv[v] = S; WvD[v] = W * invdeg[v];
  }
}

// ---------------- COO pass C: z[c] += WvD[r] ----------------
__global__ __launch_bounds__(256) void k_cooC8(const int* __restrict__ rows, const int* __restrict__ cols,
                                               const float* __restrict__ WvD, float* __restrict__ z8) {
  int i = (blockIdx.x * 256 + threadIdx.x) * 4;
  if (i < NNZ) {
    float* zp = z8 + (blockIdx.x & 7) * SE;
    int4 r = *(const int4*)(rows + i);
    int4 c = *(const int4*)(cols + i);
    atomicAdd(&zp[c.x], WvD[r.x]);
    atomicAdd(&zp[c.y], WvD[r.y]);
    atomicAdd(&zp[c.z], WvD[r.z]);
    atomicAdd(&zp[c.w], WvD[r.w]);
  }
}

// ---------------- merge z ----------------
__global__ __launch_bounds__(256) void k_mergeZ(const float* __restrict__ z8, float* __restrict__ zM) {
  int j = blockIdx.x * 256 + threadIdx.x;
  if (j < N_E) {
    float s = 0.f;
#pragma unroll
    for (int p = 0; p < 8; p++) s += z8[p * SE + j];
    zM[j] = s;
  }
}

// ---------------- COO pass D: Z2[r] += z[c]  (merged inside k_dense) ----------------
__global__ __launch_bounds__(256) void k_cooD8(const int* __restrict__ rows, const int* __restrict__ cols,
                                               const float* __restrict__ zM, float* __restrict__ Z28) {
  int i = (blockIdx.x * 256 + threadIdx.x) * 4;
  if (i < NNZ) {
    float* zp = Z28 + (blockIdx.x & 7) * SV;
    int4 r = *(const int4*)(rows + i);
    int4 c = *(const int4*)(cols + i);
    atomicAdd(&zp[r.x], zM[c.x]);
    atomicAdd(&zp[r.y], zM[c.y]);
    atomicAdd(&zp[r.z], zM[c.z]);
    atomicAdd(&zp[r.w], zM[c.w]);
  }
}

// ---------------- fused input weight (parallel): W0f = W0@Wl0; b0f = b0@Wl0 + bl0 ----------------
__global__ __launch_bounds__(128) void k_fusew(const float* __restrict__ W0, const float* __restrict__ b0,
                                               const float* __restrict__ Wl0, const float* __restrict__ bl0,
                                               float* __restrict__ W0f, float* __restrict__ b0f) {
  int n = threadIdx.x;
  int d = blockIdx.x;
  if (d < D_IN) {
    float acc = 0.f;
    for (int k = 0; k < H; k++) acc += W0[d * H + k] * Wl0[k * H + n];
    W0f[d * H + n] = acc;
  } else {
    float accb = bl0[n];
    for (int k = 0; k < H; k++) accb += b0[k] * Wl0[k * H + n];
    b0f[n] = accb;
  }
}

// ---------------- dense pass: h1 in-register; 4 weighted colsums -> partialT[c][b] ----------------
__global__ __launch_bounds__(256) void k_dense(const float* __restrict__ X, const float* __restrict__ W0f,
                                               const float* __restrict__ b0f,
                                               const float* __restrict__ rdegf, const float* __restrict__ Wv,
                                               const float* __restrict__ Sv, const float* __restrict__ Z28,
                                               float* __restrict__ partialT, int nblk) {
  __shared__ float Ws[D_IN * H];
  __shared__ float Bs[H];
  __shared__ float l0[128], l1[128], l2[128], l3[128];
  int t = threadIdx.x;
  for (int i = t; i < D_IN * H; i += 256) Ws[i] = W0f[i];
  if (t < H) Bs[t] = b0f[t];
  if (t < 128) { l0[t] = 0.f; l1[t] = 0.f; l2[t] = 0.f; l3[t] = 0.f; }
  __syncthreads();
  int lane = t & 63, eg = lane >> 4, sl = lane & 15;
  int cg = sl * 8;
  float c0[8] = {0,0,0,0,0,0,0,0}, c1[8] = {0,0,0,0,0,0,0,0};
  float c2[8] = {0,0,0,0,0,0,0,0}, c3[8] = {0,0,0,0,0,0,0,0};
  for (int it = 0; it < 16; ++it) {
    int row = blockIdx.x * 256 + it * 16 + (t >> 4);
    if (row < N_V) {
      float acc[8];
#pragma unroll
      for (int j = 0; j < 8; j++) acc[j] = Bs[cg + j];
#pragma unroll
      for (int k = 0; k < D_IN; k++) {
        float xv = X[row * D_IN + k];
#pragma unroll
        for (int j = 0; j < 8; j++) acc[j] += xv * Ws[k * H + cg + j];
      }
      float Z2 = 0.f;
#pragma unroll
      for (int p = 0; p < 8; p++) Z2 += Z28[p * SV + row];
      float g1 = Wv[row];
      float g2 = rdegf[row] + Sv[row];
      float g3 = g1 + Z2;
#pragma unroll
      for (int j = 0; j < 8; j++) {
        float a = acc[j];
        c0[j] += a; c1[j] += g1 * a; c2[j] += g2 * a; c3[j] += g3 * a;
      }
    }
  }
#pragma unroll
  for (int j = 0; j < 8; j++) {
    float v0 = c0[j], v1 = c1[j], v2 = c2[j], v3 = c3[j];
    v0 += __shfl_xor(v0, 16); v0 += __shfl_xor(v0, 32);
    v1 += __shfl_xor(v1, 16); v1 += __shfl_xor(v1, 32);
    v2 += __shfl_xor(v2, 16); v2 += __shfl_xor(v2, 32);
    v3 += __shfl_xor(v3, 16); v3 += __shfl_xor(v3, 32);
    if (eg == 0) {
      atomicAdd(&l0[cg + j], v0);
      atomicAdd(&l1[cg + j], v1);
      atomicAdd(&l2[cg + j], v2);
      atomicAdd(&l3[cg + j], v3);
    }
  }
  __syncthreads();
  if (t < 128) {
    int b = blockIdx.x;
    partialT[(0 * 128 + t) * nblk + b] = l0[t];
    partialT[(1 * 128 + t) * nblk + b] = l1[t];
    partialT[(2 * 128 + t) * nblk + b] = l2[t];
    partialT[(3 * 128 + t) * nblk + b] = l3[t];
  }
}

// ---------------- reduce partialT[512][nblk] -> cs[512]  (one wave per column) ----------------
__global__ __launch_bounds__(256) void k_red(const float* __restrict__ partialT, int nblk,
                                             float* __restrict__ cs) {
  int t = threadIdx.x, lane = t & 63, wv = t >> 6;
  int c = blockIdx.x * 4 + wv;
  float s = 0.f;
  for (int k = lane; k < nblk; k += 64) s += partialT[c * nblk + k];
  s += __shfl_xor(s, 1); s += __shfl_xor(s, 2); s += __shfl_xor(s, 4);
  s += __shfl_xor(s, 8); s += __shfl_xor(s, 16); s += __shfl_xor(s, 32);
  if (lane == 0) cs[c] = s;
}

// ---------------- final: push Wl1, output heads ----------------
__global__ __launch_bounds__(128) void k_final(const float* __restrict__ cs,
                                               const float* __restrict__ qsum,
                                               const float* __restrict__ Wl1, const float* __restrict__ bl1,
                                               const float* __restrict__ Wo0, const float* __restrict__ bo0,
                                               const float* __restrict__ Wo1, const float* __restrict__ bo1,
                                               float* __restrict__ out) {
  __shared__ float red[128];
  int t = threadIdx.x;
  float sx = 0.f, se = 0.f;
  for (int k = 0; k < H; k++) {
    float wv = Wl1[k * H + t];
    float csx = cs[k] + cs[128 + k];          // colsum(a2) = colsum(h1) + sum w_k e1_k
    sx += (csx + cs[384 + k]) * wv;
    se += cs[256 + k] * wv;
  }
  float Q = qsum[0];
  sx += ((float)N_V + Q) * bl1[t];
  se += (float)NNZ * bl1[t];
  red[t] = sx * (1.f / (float)N_V) * Wo0[t] + se * (1.f / (float)N_E) * Wo1[t];
  __syncthreads();
  for (int o = 64; o > 0; o >>= 1) {
    if (t < o) red[t] += red[t + o];
    __syncthreads();
  }
  if (t == 0) out[0] = red[0] + bo0[0] + bo1[0];
}

extern "C" void kernel_launch(void* const* d_in, const int* in_sizes, int n_in,
                              void* d_out, int out_size, void* d_ws, size_t ws_size,
                              hipStream_t stream) {
  const float* x0in = (const float*)d_in[0];
  const int* rows   = (const int*)d_in[2];
  const int* cols   = (const int*)d_in[3];
  const float* W0   = (const float*)d_in[4];
  const float* b0   = (const float*)d_in[5];
  const float* Wl0  = (const float*)d_in[8];
  const float* bl0  = (const float*)d_in[9];
  const float* Wl1  = (const float*)d_in[10];
  const float* bl1  = (const float*)d_in[11];
  const float* Wo0  = (const float*)d_in[12];
  const float* bo0  = (const float*)d_in[13];
  const float* Wo1  = (const float*)d_in[14];
  const float* bo1  = (const float*)d_in[15];
  float* out = (float*)d_out;
  char* ws = (char*)d_ws;

  // ---- workspace layout (zero region first) ----
  int*    rcnt8 = (int*)(ws + 0);            // 8*SV int  = 3,203,072
  int*    ccnt8 = (int*)(ws + 3203072);      // 8*SE int  = 6,406,144
  float*  w8    = (float*)(ws + 9609216);    // 8*SE f32  = 6,406,144
  float*  WS8   = (float*)(ws + 16015360);   // 8*SE f32  = 6,406,144 (Wv,Sv interleaved)
  float*  z8    = (float*)(ws + 22421504);   // 8*SE f32  = 6,406,144
  float*  Z28   = (float*)(ws + 28827648);   // 8*SV f32  = 3,203,072
  float*  qsum  = (float*)(ws + 32030720);   // 4         -> memset [0, 32030724)
  float*  rdegf = (float*)(ws + 32030976);   // 400,384
  float*  invdg = (float*)(ws + 32431360);   // 400,384
  float*  cn    = (float*)(ws + 32831744);   // 800,768
  float2* wn    = (float2*)(ws + 33632512);  // 1,601,536
  float*  Wv    = (float*)(ws + 35234048);   // 400,384
  float*  Sv    = (float*)(ws + 35634432);   // 400,384
  float*  WvD   = (float*)(ws + 36034816);   // 400,384
  float*  zM    = (float*)(ws + 36435200);   // 800,768
  float*  W0f   = (float*)(ws + 37235968);   // 7,168
  float*  b0f   = (float*)(ws + 37243136);   // 512
  float*  partialT = (float*)(ws + 37243648);// 512*391*4 = 800,768
  float*  cs    = (float*)(ws + 38044416);   // 2,048
  // total: 38,046,464 B

  const int NBLK = (N_V + 255) / 256;        // 391
  const int GCOO = (NNZ / 4 + 255) / 256;    // 782
  const int GNE  = (N_E + 255) / 256;        // 782
  const int GNV  = (N_V + 255) / 256;        // 391

  hipMemsetAsync(ws, 0, 32030724, stream);
  k_hist8<<<dim3(GCOO), dim3(256), 0, stream>>>(rows, cols, rcnt8, ccnt8);
  k_mergeRC<<<dim3(GNE), dim3(256), 0, stream>>>(rcnt8, ccnt8, rdegf, invdg, cn);
  k_cooA8<<<dim3(GCOO), dim3(256), 0, stream>>>(rows, cols, invdg, w8);
  k_mergeW<<<dim3(GNE), dim3(256), 0, stream>>>(w8, cn, wn, qsum);
  k_cooB8<<<dim3(GCOO), dim3(256), 0, stream>>>(rows, cols, wn, WS8);
  k_mergeWS<<<dim3(GNV), dim3(256), 0, stream>>>(WS8, invdg, Wv, Sv, WvD);
  k_cooC8<<<dim3(GCOO), dim3(256), 0, stream>>>(rows, cols, WvD, z8);
  k_mergeZ<<<dim3(GNE), dim3(256), 0, stream>>>(z8, zM);
  k_cooD8<<<dim3(GCOO), dim3(256), 0, stream>>>(rows, cols, zM, Z28);
  k_fusew<<<dim3(D_IN + 1), dim3(128), 0, stream>>>(W0, b0, Wl0, bl0, W0f, b0f);
  k_dense<<<dim3(NBLK), dim3(256), 0, stream>>>(x0in, W0f, b0f, rdegf, Wv, Sv, Z28, partialT, NBLK);
  k_red<<<dim3(128), dim3(256), 0, stream>>>(partialT, NBLK, cs);
  k_final<<<dim3(1), dim3(128), 0, stream>>>(cs, qsum, Wl1, bl1, Wo0, bo0, Wo1, bo1, out);
}

// Round 9
// 201.687 us; speedup vs baseline: 2.9883x; 2.2203x over previous
//
#include <hip/hip_runtime.h>
#include <stdint.h>

#define N_V 100000
#define N_E 200000
#define NNZ 800000
#define D_IN 14
#define H 128

#define CAP 6144          // records per bucket (mean 4096, +32 sigma)
#define NBUCK 196

// ---------------- bin COO records by dest>>shift into fixed-capacity buckets ----------------
__global__ __launch_bounds__(256) void k_bin(const int* __restrict__ keys, const int* __restrict__ vals,
                                             int shift, uint2* __restrict__ binned, int* __restrict__ cnt) {
  __shared__ int bcnt[256], bsc[256], bex[256], gb[256];
  __shared__ uint2 recs[4096];
  __shared__ unsigned char bid[4096];
  int t = threadIdx.x;
  bcnt[t] = 0;
  __syncthreads();
  int base = blockIdx.x * 4096;
  int k_[16], v_[16], lp[16];
  short bb[16];
#pragma unroll
  for (int u = 0; u < 16; u++) {
    int i = base + u * 256 + t;
    if (i < NNZ) {
      k_[u] = keys[i]; v_[u] = vals[i];
      int b = k_[u] >> shift;
      bb[u] = (short)b;
      lp[u] = atomicAdd(&bcnt[b], 1);
    } else bb[u] = -1;
  }
  __syncthreads();
  bsc[t] = bcnt[t];
  __syncthreads();
  for (int o = 1; o < 256; o <<= 1) {
    int x = (t >= o) ? bsc[t - o] : 0;
    __syncthreads();
    bsc[t] += x;
    __syncthreads();
  }
  bex[t] = bsc[t] - bcnt[t];
  __syncthreads();
#pragma unroll
  for (int u = 0; u < 16; u++) {
    if (bb[u] >= 0) {
      int p = bex[bb[u]] + lp[u];
      recs[p] = make_uint2((unsigned)k_[u], (unsigned)v_[u]);
      bid[p] = (unsigned char)bb[u];
    }
  }
  if (t < NBUCK && bcnt[t] > 0) gb[t] = t * CAP + atomicAdd(&cnt[t], bcnt[t]);
  __syncthreads();
  int total = bsc[255];
  for (int p = t; p < total; p += 256) {
    int b = bid[p];
    binned[gb[b] + (p - bex[b])] = recs[p];
  }
}

// ---------------- fine pass: vertex degree histogram -> rdegf, invdg ----------------
__global__ __launch_bounds__(256) void k_fhist(const uint2* __restrict__ binnedR, const int* __restrict__ cntR,
                                               float* __restrict__ rdegf, float* __restrict__ invdg) {
  __shared__ int d_l[512];
  int t = threadIdx.x;
  int b = blockIdx.x, kb = b << 9;
  d_l[t] = 0; d_l[t + 256] = 0;
  __syncthreads();
  int cnt = cntR[b];
  const uint2* rec = binnedR + (size_t)b * CAP;
  int p = t;
  for (; p + 768 < cnt; p += 1024) {
    uint2 r0 = rec[p], r1 = rec[p + 256], r2 = rec[p + 512], r3 = rec[p + 768];
    atomicAdd(&d_l[r0.x - kb], 1); atomicAdd(&d_l[r1.x - kb], 1);
    atomicAdd(&d_l[r2.x - kb], 1); atomicAdd(&d_l[r3.x - kb], 1);
  }
  for (; p < cnt; p += 256) atomicAdd(&d_l[rec[p].x - kb], 1);
  __syncthreads();
#pragma unroll
  for (int q = 0; q < 2; q++) {
    int r = t + q * 256;
    int v = kb + r;
    if (v < N_V) {
      int s = d_l[r];
      rdegf[v] = (float)s;
      invdg[v] = 1.f / (float)(s > 0 ? s : 1);
    }
  }
}

// ---------------- fine pass A: edge histogram + w_j = sum invdeg; wn=(w,n); qsum += w*n ----------------
__global__ __launch_bounds__(256) void k_fA(const uint2* __restrict__ binnedC, const int* __restrict__ cntC,
                                            const float* __restrict__ invdg,
                                            float2* __restrict__ wn, float* __restrict__ qsum) {
  __shared__ int n_l[1024];
  __shared__ float w_l[1024];
  __shared__ float red[256];
  int t = threadIdx.x;
  int b = blockIdx.x, kb = b << 10;
#pragma unroll
  for (int q = 0; q < 4; q++) { n_l[t + q * 256] = 0; w_l[t + q * 256] = 0.f; }
  __syncthreads();
  int cnt = cntC[b];
  const uint2* rec = binnedC + (size_t)b * CAP;
  int p = t;
  for (; p + 768 < cnt; p += 1024) {
    uint2 r0 = rec[p], r1 = rec[p + 256], r2 = rec[p + 512], r3 = rec[p + 768];
    float i0 = invdg[r0.y], i1 = invdg[r1.y], i2 = invdg[r2.y], i3 = invdg[r3.y];
    atomicAdd(&n_l[r0.x - kb], 1); atomicAdd(&w_l[r0.x - kb], i0);
    atomicAdd(&n_l[r1.x - kb], 1); atomicAdd(&w_l[r1.x - kb], i1);
    atomicAdd(&n_l[r2.x - kb], 1); atomicAdd(&w_l[r2.x - kb], i2);
    atomicAdd(&n_l[r3.x - kb], 1); atomicAdd(&w_l[r3.x - kb], i3);
  }
  for (; p < cnt; p += 256) {
    uint2 r0 = rec[p];
    atomicAdd(&n_l[r0.x - kb], 1);
    atomicAdd(&w_l[r0.x - kb], invdg[r0.y]);
  }
  __syncthreads();
  float q = 0.f;
#pragma unroll
  for (int u = 0; u < 4; u++) {
    int j = t + u * 256;
    int e = kb + j;
    if (e < N_E) {
      float n = (float)n_l[j], wf = w_l[j];
      wn[e] = make_float2(wf, n);
      q += wf * n;
    }
  }
  red[t] = q;
  __syncthreads();
  for (int o = 128; o > 0; o >>= 1) {
    if (t < o) red[t] += red[t + o];
    __syncthreads();
  }
  if (t == 0) atomicAdd(qsum, red[0]);
}

// ---------------- fine pass B: Wv[r]+=w[c], Sv[r]+=n[c]; WvD = Wv*invdeg ----------------
__global__ __launch_bounds__(256) void k_fB(const uint2* __restrict__ binnedR, const int* __restrict__ cntR,
                                            const float2* __restrict__ wn, const float* __restrict__ invdg,
                                            float* __restrict__ Wv, float* __restrict__ Sv,
                                            float* __restrict__ WvD) {
  __shared__ float W_l[512], S_l[512];
  int t = threadIdx.x;
  int b = blockIdx.x, kb = b << 9;
  W_l[t] = 0.f; W_l[t + 256] = 0.f; S_l[t] = 0.f; S_l[t + 256] = 0.f;
  __syncthreads();
  int cnt = cntR[b];
  const uint2* rec = binnedR + (size_t)b * CAP;
  int p = t;
  for (; p + 768 < cnt; p += 1024) {
    uint2 r0 = rec[p], r1 = rec[p + 256], r2 = rec[p + 512], r3 = rec[p + 768];
    float2 a0 = wn[r0.y], a1 = wn[r1.y], a2 = wn[r2.y], a3 = wn[r3.y];
    atomicAdd(&W_l[r0.x - kb], a0.x); atomicAdd(&S_l[r0.x - kb], a0.y);
    atomicAdd(&W_l[r1.x - kb], a1.x); atomicAdd(&S_l[r1.x - kb], a1.y);
    atomicAdd(&W_l[r2.x - kb], a2.x); atomicAdd(&S_l[r2.x - kb], a2.y);
    atomicAdd(&W_l[r3.x - kb], a3.x); atomicAdd(&S_l[r3.x - kb], a3.y);
  }
  for (; p < cnt; p += 256) {
    uint2 r0 = rec[p];
    float2 a0 = wn[r0.y];
    atomicAdd(&W_l[r0.x - kb], a0.x); atomicAdd(&S_l[r0.x - kb], a0.y);
  }
  __syncthreads();
#pragma unroll
  for (int q = 0; q < 2; q++) {
    int r = t + q * 256;
    int v = kb + r;
    if (v < N_V) {
      float W = W_l[r];
      Wv[v] = W; Sv[v] = S_l[r]; WvD[v] = W * invdg[v];
    }
  }
}

// ---------------- fine pass C: z[c] += WvD[r] -> zM ----------------
__global__ __launch_bounds__(256) void k_fC(const uint2* __restrict__ binnedC, const int* __restrict__ cntC,
                                            const float* __restrict__ WvD, float* __restrict__ zM) {
  __shared__ float z_l[1024];
  int t = threadIdx.x;
  int b = blockIdx.x, kb = b << 10;
#pragma unroll
  for (int q = 0; q < 4; q++) z_l[t + q * 256] = 0.f;
  __syncthreads();
  int cnt = cntC[b];
  const uint2* rec = binnedC + (size_t)b * CAP;
  int p = t;
  for (; p + 768 < cnt; p += 1024) {
    uint2 r0 = rec[p], r1 = rec[p + 256], r2 = rec[p + 512], r3 = rec[p + 768];
    float a0 = WvD[r0.y], a1 = WvD[r1.y], a2 = WvD[r2.y], a3 = WvD[r3.y];
    atomicAdd(&z_l[r0.x - kb], a0); atomicAdd(&z_l[r1.x - kb], a1);
    atomicAdd(&z_l[r2.x - kb], a2); atomicAdd(&z_l[r3.x - kb], a3);
  }
  for (; p < cnt; p += 256) {
    uint2 r0 = rec[p];
    atomicAdd(&z_l[r0.x - kb], WvD[r0.y]);
  }
  __syncthreads();
#pragma unroll
  for (int q = 0; q < 4; q++) {
    int j = t + q * 256;
    int e = kb + j;
    if (e < N_E) zM[e] = z_l[j];
  }
}

// ---------------- fine pass D: Z2[r] += zM[c] ----------------
__global__ __launch_bounds__(256) void k_fD(const uint2* __restrict__ binnedR, const int* __restrict__ cntR,
                                            const float* __restrict__ zM, float* __restrict__ Z2) {
  __shared__ float Z_l[512];
  int t = threadIdx.x;
  int b = blockIdx.x, kb = b << 9;
  Z_l[t] = 0.f; Z_l[t + 256] = 0.f;
  __syncthreads();
  int cnt = cntR[b];
  const uint2* rec = binnedR + (size_t)b * CAP;
  int p = t;
  for (; p + 768 < cnt; p += 1024) {
    uint2 r0 = rec[p], r1 = rec[p + 256], r2 = rec[p + 512], r3 = rec[p + 768];
    float a0 = zM[r0.y], a1 = zM[r1.y], a2 = zM[r2.y], a3 = zM[r3.y];
    atomicAdd(&Z_l[r0.x - kb], a0); atomicAdd(&Z_l[r1.x - kb], a1);
    atomicAdd(&Z_l[r2.x - kb], a2); atomicAdd(&Z_l[r3.x - kb], a3);
  }
  for (; p < cnt; p += 256) {
    uint2 r0 = rec[p];
    atomicAdd(&Z_l[r0.x - kb], zM[r0.y]);
  }
  __syncthreads();
#pragma unroll
  for (int q = 0; q < 2; q++) {
    int r = t + q * 256;
    int v = kb + r;
    if (v < N_V) Z2[v] = Z_l[r];
  }
}

// ---------------- fused input weight (parallel): W0f = W0@Wl0; b0f = b0@Wl0 + bl0 ----------------
__global__ __launch_bounds__(128) void k_fusew(const float* __restrict__ W0, const float* __restrict__ b0,
                                               const float* __restrict__ Wl0, const float* __restrict__ bl0,
                                               float* __restrict__ W0f, float* __restrict__ b0f) {
  int n = threadIdx.x;
  int d = blockIdx.x;
  if (d < D_IN) {
    float acc = 0.f;
    for (int k = 0; k < H; k++) acc += W0[d * H + k] * Wl0[k * H + n];
    W0f[d * H + n] = acc;
  } else {
    float accb = bl0[n];
    for (int k = 0; k < H; k++) accb += b0[k] * Wl0[k * H + n];
    b0f[n] = accb;
  }
}

// ---------------- dense pass: h1 in-register (weights in VGPRs); 4 weighted colsums ----------------
__global__ __launch_bounds__(256) void k_dense(const float* __restrict__ X, const float* __restrict__ W0f,
                                               const float* __restrict__ b0f,
                                               const float* __restrict__ rdegf, const float* __restrict__ Wv,
                                               const float* __restrict__ Sv, const float* __restrict__ Z2,
                                               float* __restrict__ partialT, int nblk) {
  __shared__ float l0[128], l1[128], l2[128], l3[128];
  int t = threadIdx.x;
  int lane = t & 63, eg = lane >> 4, sl = lane & 15;
  int cg = sl * 8;
  float Wr[D_IN * 8];
#pragma unroll
  for (int k = 0; k < D_IN; k++) {
    float4 a = *(const float4*)&W0f[k * H + cg];
    float4 b = *(const float4*)&W0f[k * H + cg + 4];
    Wr[k * 8 + 0] = a.x; Wr[k * 8 + 1] = a.y; Wr[k * 8 + 2] = a.z; Wr[k * 8 + 3] = a.w;
    Wr[k * 8 + 4] = b.x; Wr[k * 8 + 5] = b.y; Wr[k * 8 + 6] = b.z; Wr[k * 8 + 7] = b.w;
  }
  float Bs[8];
  {
    float4 a = *(const float4*)&b0f[cg];
    float4 b = *(const float4*)&b0f[cg + 4];
    Bs[0] = a.x; Bs[1] = a.y; Bs[2] = a.z; Bs[3] = a.w;
    Bs[4] = b.x; Bs[5] = b.y; Bs[6] = b.z; Bs[7] = b.w;
  }
  if (t < 128) { l0[t] = 0.f; l1[t] = 0.f; l2[t] = 0.f; l3[t] = 0.f; }
  __syncthreads();
  const float2* X2 = (const float2*)X;
  float c0[8] = {0,0,0,0,0,0,0,0}, c1[8] = {0,0,0,0,0,0,0,0};
  float c2[8] = {0,0,0,0,0,0,0,0}, c3[8] = {0,0,0,0,0,0,0,0};
  for (int it = 0; it < 16; ++it) {
    int row = blockIdx.x * 256 + it * 16 + (t >> 4);
    if (row < N_V) {
      float acc[8];
#pragma unroll
      for (int j = 0; j < 8; j++) acc[j] = Bs[j];
#pragma unroll
      for (int q = 0; q < 7; q++) {
        float2 xp = X2[row * 7 + q];
#pragma unroll
        for (int j = 0; j < 8; j++) acc[j] += xp.x * Wr[(2 * q) * 8 + j];
#pragma unroll
        for (int j = 0; j < 8; j++) acc[j] += xp.y * Wr[(2 * q + 1) * 8 + j];
      }
      float g1 = Wv[row];
      float g2 = rdegf[row] + Sv[row];
      float g3 = g1 + Z2[row];
#pragma unroll
      for (int j = 0; j < 8; j++) {
        float a = acc[j];
        c0[j] += a; c1[j] += g1 * a; c2[j] += g2 * a; c3[j] += g3 * a;
      }
    }
  }
#pragma unroll
  for (int j = 0; j < 8; j++) {
    float v0 = c0[j], v1 = c1[j], v2 = c2[j], v3 = c3[j];
    v0 += __shfl_xor(v0, 16); v0 += __shfl_xor(v0, 32);
    v1 += __shfl_xor(v1, 16); v1 += __shfl_xor(v1, 32);
    v2 += __shfl_xor(v2, 16); v2 += __shfl_xor(v2, 32);
    v3 += __shfl_xor(v3, 16); v3 += __shfl_xor(v3, 32);
    if (eg == 0) {
      atomicAdd(&l0[cg + j], v0);
      atomicAdd(&l1[cg + j], v1);
      atomicAdd(&l2[cg + j], v2);
      atomicAdd(&l3[cg + j], v3);
    }
  }
  __syncthreads();
  if (t < 128) {
    int b = blockIdx.x;
    partialT[(0 * 128 + t) * nblk + b] = l0[t];
    partialT[(1 * 128 + t) * nblk + b] = l1[t];
    partialT[(2 * 128 + t) * nblk + b] = l2[t];
    partialT[(3 * 128 + t) * nblk + b] = l3[t];
  }
}

// ---------------- reduce partialT[512][nblk] -> cs[512] ----------------
__global__ __launch_bounds__(256) void k_red(const float* __restrict__ partialT, int nblk,
                                             float* __restrict__ cs) {
  int t = threadIdx.x, lane = t & 63, wv = t >> 6;
  int c = blockIdx.x * 4 + wv;
  float s = 0.f;
  for (int k = lane; k < nblk; k += 64) s += partialT[c * nblk + k];
  s += __shfl_xor(s, 1); s += __shfl_xor(s, 2); s += __shfl_xor(s, 4);
  s += __shfl_xor(s, 8); s += __shfl_xor(s, 16); s += __shfl_xor(s, 32);
  if (lane == 0) cs[c] = s;
}

// ---------------- final: push Wl1, output heads ----------------
__global__ __launch_bounds__(128) void k_final(const float* __restrict__ cs,
                                               const float* __restrict__ qsum,
                                               const float* __restrict__ Wl1, const float* __restrict__ bl1,
                                               const float* __restrict__ Wo0, const float* __restrict__ bo0,
                                               const float* __restrict__ Wo1, const float* __restrict__ bo1,
                                               float* __restrict__ out) {
  __shared__ float red[128];
  int t = threadIdx.x;
  float sx = 0.f, se = 0.f;
  for (int k = 0; k < H; k++) {
    float wv = Wl1[k * H + t];
    float csx = cs[k] + cs[128 + k];          // colsum(a2) = colsum(h1) + sum w_k e1_k
    sx += (csx + cs[384 + k]) * wv;
    se += cs[256 + k] * wv;
  }
  float Q = qsum[0];
  sx += ((float)N_V + Q) * bl1[t];
  se += (float)NNZ * bl1[t];
  red[t] = sx * (1.f / (float)N_V) * Wo0[t] + se * (1.f / (float)N_E) * Wo1[t];
  __syncthreads();
  for (int o = 64; o > 0; o >>= 1) {
    if (t < o) red[t] += red[t + o];
    __syncthreads();
  }
  if (t == 0) out[0] = red[0] + bo0[0] + bo1[0];
}

extern "C" void kernel_launch(void* const* d_in, const int* in_sizes, int n_in,
                              void* d_out, int out_size, void* d_ws, size_t ws_size,
                              hipStream_t stream) {
  const float* x0in = (const float*)d_in[0];
  const int* rows   = (const int*)d_in[2];
  const int* cols   = (const int*)d_in[3];
  const float* W0   = (const float*)d_in[4];
  const float* b0   = (const float*)d_in[5];
  const float* Wl0  = (const float*)d_in[8];
  const float* bl0  = (const float*)d_in[9];
  const float* Wl1  = (const float*)d_in[10];
  const float* bl1  = (const float*)d_in[11];
  const float* Wo0  = (const float*)d_in[12];
  const float* bo0  = (const float*)d_in[13];
  const float* Wo1  = (const float*)d_in[14];
  const float* bo1  = (const float*)d_in[15];
  float* out = (float*)d_out;
  char* ws = (char*)d_ws;

  // ---- workspace layout (only [0, 2052) needs zeroing) ----
  int*    cntR  = (int*)(ws + 0);            // 196 ints (pad 1024)
  int*    cntC  = (int*)(ws + 1024);         // 196 ints (pad 1024)
  float*  qsum  = (float*)(ws + 2048);       // 4        -> memset [0, 2052)
  float*  rdegf = (float*)(ws + 4096);       // 400,000
  float*  invdg = (float*)(ws + 404096);     // 400,000
  float*  Wv    = (float*)(ws + 804096);     // 400,000
  float*  Sv    = (float*)(ws + 1204096);    // 400,000
  float*  WvD   = (float*)(ws + 1604096);    // 400,000
  float*  Z2    = (float*)(ws + 2004096);    // 400,000
  float2* wn    = (float2*)(ws + 2404096);   // 1,600,000
  float*  zM    = (float*)(ws + 4004096);    // 800,000
  float*  W0f   = (float*)(ws + 4804096);    // 7,168
  float*  b0f   = (float*)(ws + 4811264);    // 512
  float*  partialT = (float*)(ws + 4811776); // 512*391*4 = 800,768
  float*  cs    = (float*)(ws + 5612544);    // 2,048
  uint2*  binnedR = (uint2*)(ws + 5614592);  // 196*6144*8 = 9,633,792
  uint2*  binnedC = (uint2*)(ws + 15248384); // 9,633,792
  // total: 24,882,176 B

  const int NBLK = (N_V + 255) / 256;        // 391

  hipMemsetAsync(ws, 0, 2052, stream);
  k_bin<<<dim3(NBUCK), dim3(256), 0, stream>>>(rows, cols, 9, binnedR, cntR);
  k_bin<<<dim3(NBUCK), dim3(256), 0, stream>>>(cols, rows, 10, binnedC, cntC);
  k_fhist<<<dim3(NBUCK), dim3(256), 0, stream>>>(binnedR, cntR, rdegf, invdg);
  k_fA<<<dim3(NBUCK), dim3(256), 0, stream>>>(binnedC, cntC, invdg, wn, qsum);
  k_fB<<<dim3(NBUCK), dim3(256), 0, stream>>>(binnedR, cntR, wn, invdg, Wv, Sv, WvD);
  k_fC<<<dim3(NBUCK), dim3(256), 0, stream>>>(binnedC, cntC, WvD, zM);
  k_fD<<<dim3(NBUCK), dim3(256), 0, stream>>>(binnedR, cntR, zM, Z2);
  k_fusew<<<dim3(D_IN + 1), dim3(128), 0, stream>>>(W0, b0, Wl0, bl0, W0f, b0f);
  k_dense<<<dim3(NBLK), dim3(256), 0, stream>>>(x0in, W0f, b0f, rdegf, Wv, Sv, Z2, partialT, NBLK);
  k_red<<<dim3(128), dim3(256), 0, stream>>>(partialT, NBLK, cs);
  k_final<<<dim3(1), dim3(128), 0, stream>>>(cs, qsum, Wl1, bl1, Wo0, bo0, Wo1, bo1, out);
}

// Round 10
// 182.364 us; speedup vs baseline: 3.3050x; 1.1060x over previous
//
#include <hip/hip_runtime.h>
#include <stdint.h>

#define N_V 100000
#define N_E 200000
#define NNZ 800000
#define D_IN 14
#define H 128

#define RSH 8             // row bucket = 256 vertices
#define CSH 9             // col bucket = 512 edges
#define NB_R 391          // ceil(N_V/256)
#define NB_C 391          // ceil(N_E/512)
#define CAPR 3072         // mean 2048 + ~23 sigma
#define CAPC 3072
#define VMASK 0x3FFFFu

// ---------------- merged bin (both directions) + fusew rider blocks ----------------
__global__ __launch_bounds__(1024) void k_bin2(const int* __restrict__ rows, const int* __restrict__ cols,
                                               const float* __restrict__ W0, const float* __restrict__ b0,
                                               const float* __restrict__ Wl0, const float* __restrict__ bl0,
                                               float* __restrict__ W0f, float* __restrict__ b0f,
                                               unsigned* __restrict__ binnedR, int* __restrict__ cntR,
                                               unsigned* __restrict__ binnedC, int* __restrict__ cntC) {
  int t = threadIdx.x;
  if (blockIdx.x >= 196) {          // fusew rider: W0f = W0@Wl0, b0f = b0@Wl0 + bl0
    if (t < 128) {
      int n = t, d = blockIdx.x - 196;
      if (d < D_IN) {
        float acc = 0.f;
        for (int k = 0; k < H; k++) acc += W0[d * H + k] * Wl0[k * H + n];
        W0f[d * H + n] = acc;
      } else {
        float accb = bl0[n];
        for (int k = 0; k < H; k++) accb += b0[k] * Wl0[k * H + n];
        b0f[n] = accb;
      }
    }
    return;
  }
  __shared__ int bcnt[512], bsc[512], bex[512], gb[512];
  __shared__ unsigned recs[4096];
  __shared__ unsigned short bid[4096];
  int r_[4], c_[4], lp[4], bb[4];
  int base = blockIdx.x * 4096;
#pragma unroll
  for (int u = 0; u < 4; u++) {
    int i = base + u * 1024 + t;
    if (i < NNZ) { r_[u] = rows[i]; c_[u] = cols[i]; } else r_[u] = -1;
  }
  // ---- phase R: key=row, val=col ----
  if (t < 512) bcnt[t] = 0;
  __syncthreads();
#pragma unroll
  for (int u = 0; u < 4; u++) {
    if (r_[u] >= 0) { int b = r_[u] >> RSH; bb[u] = b; lp[u] = atomicAdd(&bcnt[b], 1); }
    else bb[u] = -1;
  }
  __syncthreads();
  if (t < 512) bsc[t] = bcnt[t];
  __syncthreads();
  for (int o = 1; o < 512; o <<= 1) {
    int x = (t < 512 && t >= o) ? bsc[t - o] : 0;
    __syncthreads();
    if (t < 512) bsc[t] += x;
    __syncthreads();
  }
  if (t < 512) bex[t] = bsc[t] - bcnt[t];
  __syncthreads();
#pragma unroll
  for (int u = 0; u < 4; u++) {
    if (bb[u] >= 0) {
      int p = bex[bb[u]] + lp[u];
      recs[p] = ((unsigned)(r_[u] & 255) << 18) | (unsigned)c_[u];
      bid[p] = (unsigned short)bb[u];
    }
  }
  if (t < NB_R && bcnt[t] > 0) gb[t] = t * CAPR + atomicAdd(&cntR[t], bcnt[t]);
  __syncthreads();
  int total = bsc[511];
  for (int p = t; p < total; p += 1024) {
    int b = bid[p];
    binnedR[gb[b] + (p - bex[b])] = recs[p];
  }
  __syncthreads();
  // ---- phase C: key=col, val=row ----
  if (t < 512) bcnt[t] = 0;
  __syncthreads();
#pragma unroll
  for (int u = 0; u < 4; u++) {
    if (r_[u] >= 0) { int b = c_[u] >> CSH; bb[u] = b; lp[u] = atomicAdd(&bcnt[b], 1); }
    else bb[u] = -1;
  }
  __syncthreads();
  if (t < 512) bsc[t] = bcnt[t];
  __syncthreads();
  for (int o = 1; o < 512; o <<= 1) {
    int x = (t < 512 && t >= o) ? bsc[t - o] : 0;
    __syncthreads();
    if (t < 512) bsc[t] += x;
    __syncthreads();
  }
  if (t < 512) bex[t] = bsc[t] - bcnt[t];
  __syncthreads();
#pragma unroll
  for (int u = 0; u < 4; u++) {
    if (bb[u] >= 0) {
      int p = bex[bb[u]] + lp[u];
      recs[p] = ((unsigned)(c_[u] & 511) << 18) | (unsigned)r_[u];
      bid[p] = (unsigned short)bb[u];
    }
  }
  if (t < NB_C && bcnt[t] > 0) gb[t] = t * CAPC + atomicAdd(&cntC[t], bcnt[t]);
  __syncthreads();
  total = bsc[511];
  for (int p = t; p < total; p += 1024) {
    int b = bid[p];
    binnedC[gb[b] + (p - bex[b])] = recs[p];
  }
}

// ---------------- fine: vertex degree -> rdegf, invdg ----------------
__global__ __launch_bounds__(512) void k_fhist(const unsigned* __restrict__ binnedR, const int* __restrict__ cntR,
                                               float* __restrict__ rdegf, float* __restrict__ invdg) {
  __shared__ int d_l[256];
  int t = threadIdx.x, b = blockIdx.x;
  if (t < 256) d_l[t] = 0;
  __syncthreads();
  int cnt = cntR[b];
  const unsigned* rec = binnedR + (size_t)b * CAPR;
  int p = t;
  for (; p + 1536 < cnt; p += 2048) {
    unsigned a0 = rec[p], a1 = rec[p + 512], a2 = rec[p + 1024], a3 = rec[p + 1536];
    atomicAdd(&d_l[a0 >> 18], 1); atomicAdd(&d_l[a1 >> 18], 1);
    atomicAdd(&d_l[a2 >> 18], 1); atomicAdd(&d_l[a3 >> 18], 1);
  }
  for (; p < cnt; p += 512) atomicAdd(&d_l[rec[p] >> 18], 1);
  __syncthreads();
  if (t < 256) {
    int v = (b << RSH) + t;
    if (v < N_V) {
      int s = d_l[t];
      rdegf[v] = (float)s;
      invdg[v] = 1.f / (float)(s > 0 ? s : 1);
    }
  }
}

// ---------------- fine A: edge histogram + w_j; wn=(w,n); qsum += w*n ----------------
__global__ __launch_bounds__(512) void k_fA(const unsigned* __restrict__ binnedC, const int* __restrict__ cntC,
                                            const float* __restrict__ invdg,
                                            float2* __restrict__ wn, float* __restrict__ qsum) {
  __shared__ int n_l[512];
  __shared__ float w_l[512];
  __shared__ float red[512];
  int t = threadIdx.x, b = blockIdx.x;
  n_l[t] = 0; w_l[t] = 0.f;
  __syncthreads();
  int cnt = cntC[b];
  const unsigned* rec = binnedC + (size_t)b * CAPC;
  int p = t;
  for (; p + 1536 < cnt; p += 2048) {
    unsigned a0 = rec[p], a1 = rec[p + 512], a2 = rec[p + 1024], a3 = rec[p + 1536];
    float i0 = invdg[a0 & VMASK], i1 = invdg[a1 & VMASK];
    float i2 = invdg[a2 & VMASK], i3 = invdg[a3 & VMASK];
    atomicAdd(&n_l[a0 >> 18], 1); atomicAdd(&w_l[a0 >> 18], i0);
    atomicAdd(&n_l[a1 >> 18], 1); atomicAdd(&w_l[a1 >> 18], i1);
    atomicAdd(&n_l[a2 >> 18], 1); atomicAdd(&w_l[a2 >> 18], i2);
    atomicAdd(&n_l[a3 >> 18], 1); atomicAdd(&w_l[a3 >> 18], i3);
  }
  for (; p < cnt; p += 512) {
    unsigned a0 = rec[p];
    atomicAdd(&n_l[a0 >> 18], 1);
    atomicAdd(&w_l[a0 >> 18], invdg[a0 & VMASK]);
  }
  __syncthreads();
  float q = 0.f;
  int e = (b << CSH) + t;
  if (e < N_E) {
    float n = (float)n_l[t], wf = w_l[t];
    wn[e] = make_float2(wf, n);
    q = wf * n;
  }
  red[t] = q;
  __syncthreads();
  for (int o = 256; o > 0; o >>= 1) {
    if (t < o) red[t] += red[t + o];
    __syncthreads();
  }
  if (t == 0) atomicAdd(qsum, red[0]);
}

// ---------------- fine B: Wv[r]+=w[c], Sv[r]+=n[c]; WvD = Wv*invdeg ----------------
__global__ __launch_bounds__(512) void k_fB(const unsigned* __restrict__ binnedR, const int* __restrict__ cntR,
                                            const float2* __restrict__ wn, const float* __restrict__ invdg,
                                            float* __restrict__ Wv, float* __restrict__ Sv,
                                            float* __restrict__ WvD) {
  __shared__ float W_l[256], S_l[256];
  int t = threadIdx.x, b = blockIdx.x;
  if (t < 256) { W_l[t] = 0.f; S_l[t] = 0.f; }
  __syncthreads();
  int cnt = cntR[b];
  const unsigned* rec = binnedR + (size_t)b * CAPR;
  int p = t;
  for (; p + 1536 < cnt; p += 2048) {
    unsigned a0 = rec[p], a1 = rec[p + 512], a2 = rec[p + 1024], a3 = rec[p + 1536];
    float2 w0 = wn[a0 & VMASK], w1 = wn[a1 & VMASK], w2 = wn[a2 & VMASK], w3 = wn[a3 & VMASK];
    atomicAdd(&W_l[a0 >> 18], w0.x); atomicAdd(&S_l[a0 >> 18], w0.y);
    atomicAdd(&W_l[a1 >> 18], w1.x); atomicAdd(&S_l[a1 >> 18], w1.y);
    atomicAdd(&W_l[a2 >> 18], w2.x); atomicAdd(&S_l[a2 >> 18], w2.y);
    atomicAdd(&W_l[a3 >> 18], w3.x); atomicAdd(&S_l[a3 >> 18], w3.y);
  }
  for (; p < cnt; p += 512) {
    unsigned a0 = rec[p];
    float2 w0 = wn[a0 & VMASK];
    atomicAdd(&W_l[a0 >> 18], w0.x); atomicAdd(&S_l[a0 >> 18], w0.y);
  }
  __syncthreads();
  if (t < 256) {
    int v = (b << RSH) + t;
    if (v < N_V) {
      float W = W_l[t];
      Wv[v] = W; Sv[v] = S_l[t]; WvD[v] = W * invdg[v];
    }
  }
}

// ---------------- fine C: z[c] += WvD[r] -> zM ----------------
__global__ __launch_bounds__(512) void k_fC(const unsigned* __restrict__ binnedC, const int* __restrict__ cntC,
                                            const float* __restrict__ WvD, float* __restrict__ zM) {
  __shared__ float z_l[512];
  int t = threadIdx.x, b = blockIdx.x;
  z_l[t] = 0.f;
  __syncthreads();
  int cnt = cntC[b];
  const unsigned* rec = binnedC + (size_t)b * CAPC;
  int p = t;
  for (; p + 1536 < cnt; p += 2048) {
    unsigned a0 = rec[p], a1 = rec[p + 512], a2 = rec[p + 1024], a3 = rec[p + 1536];
    float v0 = WvD[a0 & VMASK], v1 = WvD[a1 & VMASK], v2 = WvD[a2 & VMASK], v3 = WvD[a3 & VMASK];
    atomicAdd(&z_l[a0 >> 18], v0); atomicAdd(&z_l[a1 >> 18], v1);
    atomicAdd(&z_l[a2 >> 18], v2); atomicAdd(&z_l[a3 >> 18], v3);
  }
  for (; p < cnt; p += 512) {
    unsigned a0 = rec[p];
    atomicAdd(&z_l[a0 >> 18], WvD[a0 & VMASK]);
  }
  __syncthreads();
  int e = (b << CSH) + t;
  if (e < N_E) zM[e] = z_l[t];
}

// ---------------- fine D: Z2[r] += zM[c] ----------------
__global__ __launch_bounds__(512) void k_fD(const unsigned* __restrict__ binnedR, const int* __restrict__ cntR,
                                            const float* __restrict__ zM, float* __restrict__ Z2) {
  __shared__ float Z_l[256];
  int t = threadIdx.x, b = blockIdx.x;
  if (t < 256) Z_l[t] = 0.f;
  __syncthreads();
  int cnt = cntR[b];
  const unsigned* rec = binnedR + (size_t)b * CAPR;
  int p = t;
  for (; p + 1536 < cnt; p += 2048) {
    unsigned a0 = rec[p], a1 = rec[p + 512], a2 = rec[p + 1024], a3 = rec[p + 1536];
    float v0 = zM[a0 & VMASK], v1 = zM[a1 & VMASK], v2 = zM[a2 & VMASK], v3 = zM[a3 & VMASK];
    atomicAdd(&Z_l[a0 >> 18], v0); atomicAdd(&Z_l[a1 >> 18], v1);
    atomicAdd(&Z_l[a2 >> 18], v2); atomicAdd(&Z_l[a3 >> 18], v3);
  }
  for (; p < cnt; p += 512) {
    unsigned a0 = rec[p];
    atomicAdd(&Z_l[a0 >> 18], zM[a0 & VMASK]);
  }
  __syncthreads();
  if (t < 256) {
    int v = (b << RSH) + t;
    if (v < N_V) Z2[v] = Z_l[t];
  }
}

// ---------------- dense pass: h1 in-register; 4 weighted colsums ----------------
__global__ __launch_bounds__(256) void k_dense(const float* __restrict__ X, const float* __restrict__ W0f,
                                               const float* __restrict__ b0f,
                                               const float* __restrict__ rdegf, const float* __restrict__ Wv,
                                               const float* __restrict__ Sv, const float* __restrict__ Z2,
                                               float* __restrict__ partialT, int nblk) {
  __shared__ float l0[128], l1[128], l2[128], l3[128];
  int t = threadIdx.x;
  int lane = t & 63, eg = lane >> 4, sl = lane & 15;
  int cg = sl * 8;
  float Wr[D_IN * 8];
#pragma unroll
  for (int k = 0; k < D_IN; k++) {
    float4 a = *(const float4*)&W0f[k * H + cg];
    float4 b = *(const float4*)&W0f[k * H + cg + 4];
    Wr[k * 8 + 0] = a.x; Wr[k * 8 + 1] = a.y; Wr[k * 8 + 2] = a.z; Wr[k * 8 + 3] = a.w;
    Wr[k * 8 + 4] = b.x; Wr[k * 8 + 5] = b.y; Wr[k * 8 + 6] = b.z; Wr[k * 8 + 7] = b.w;
  }
  float Bs[8];
  {
    float4 a = *(const float4*)&b0f[cg];
    float4 b = *(const float4*)&b0f[cg + 4];
    Bs[0] = a.x; Bs[1] = a.y; Bs[2] = a.z; Bs[3] = a.w;
    Bs[4] = b.x; Bs[5] = b.y; Bs[6] = b.z; Bs[7] = b.w;
  }
  if (t < 128) { l0[t] = 0.f; l1[t] = 0.f; l2[t] = 0.f; l3[t] = 0.f; }
  __syncthreads();
  const float2* X2 = (const float2*)X;
  float c0[8] = {0,0,0,0,0,0,0,0}, c1[8] = {0,0,0,0,0,0,0,0};
  float c2[8] = {0,0,0,0,0,0,0,0}, c3[8] = {0,0,0,0,0,0,0,0};
  for (int it = 0; it < 16; ++it) {
    int row = blockIdx.x * 256 + it * 16 + (t >> 4);
    if (row < N_V) {
      float acc[8];
#pragma unroll
      for (int j = 0; j < 8; j++) acc[j] = Bs[j];
#pragma unroll
      for (int q = 0; q < 7; q++) {
        float2 xp = X2[row * 7 + q];
#pragma unroll
        for (int j = 0; j < 8; j++) acc[j] += xp.x * Wr[(2 * q) * 8 + j];
#pragma unroll
        for (int j = 0; j < 8; j++) acc[j] += xp.y * Wr[(2 * q + 1) * 8 + j];
      }
      float g1 = Wv[row];
      float g2 = rdegf[row] + Sv[row];
      float g3 = g1 + Z2[row];
#pragma unroll
      for (int j = 0; j < 8; j++) {
        float a = acc[j];
        c0[j] += a; c1[j] += g1 * a; c2[j] += g2 * a; c3[j] += g3 * a;
      }
    }
  }
#pragma unroll
  for (int j = 0; j < 8; j++) {
    float v0 = c0[j], v1 = c1[j], v2 = c2[j], v3 = c3[j];
    v0 += __shfl_xor(v0, 16); v0 += __shfl_xor(v0, 32);
    v1 += __shfl_xor(v1, 16); v1 += __shfl_xor(v1, 32);
    v2 += __shfl_xor(v2, 16); v2 += __shfl_xor(v2, 32);
    v3 += __shfl_xor(v3, 16); v3 += __shfl_xor(v3, 32);
    if (eg == 0) {
      atomicAdd(&l0[cg + j], v0);
      atomicAdd(&l1[cg + j], v1);
      atomicAdd(&l2[cg + j], v2);
      atomicAdd(&l3[cg + j], v3);
    }
  }
  __syncthreads();
  if (t < 128) {
    int b = blockIdx.x;
    partialT[(0 * 128 + t) * nblk + b] = l0[t];
    partialT[(1 * 128 + t) * nblk + b] = l1[t];
    partialT[(2 * 128 + t) * nblk + b] = l2[t];
    partialT[(3 * 128 + t) * nblk + b] = l3[t];
  }
}

// ---------------- reduce partialT[512][nblk] -> cs[512] ----------------
__global__ __launch_bounds__(256) void k_red(const float* __restrict__ partialT, int nblk,
                                             float* __restrict__ cs) {
  int t = threadIdx.x, lane = t & 63, wv = t >> 6;
  int c = blockIdx.x * 4 + wv;
  float s = 0.f;
  for (int k = lane; k < nblk; k += 64) s += partialT[c * nblk + k];
  s += __shfl_xor(s, 1); s += __shfl_xor(s, 2); s += __shfl_xor(s, 4);
  s += __shfl_xor(s, 8); s += __shfl_xor(s, 16); s += __shfl_xor(s, 32);
  if (lane == 0) cs[c] = s;
}

// ---------------- final: push Wl1, output heads ----------------
__global__ __launch_bounds__(128) void k_final(const float* __restrict__ cs,
                                               const float* __restrict__ qsum,
                                               const float* __restrict__ Wl1, const float* __restrict__ bl1,
                                               const float* __restrict__ Wo0, const float* __restrict__ bo0,
                                               const float* __restrict__ Wo1, const float* __restrict__ bo1,
                                               float* __restrict__ out) {
  __shared__ float red[128];
  int t = threadIdx.x;
  float sx = 0.f, se = 0.f;
  for (int k = 0; k < H; k++) {
    float wv = Wl1[k * H + t];
    float csx = cs[k] + cs[128 + k];          // colsum(a2) = colsum(h1) + sum w_k e1_k
    sx += (csx + cs[384 + k]) * wv;
    se += cs[256 + k] * wv;
  }
  float Q = qsum[0];
  sx += ((float)N_V + Q) * bl1[t];
  se += (float)NNZ * bl1[t];
  red[t] = sx * (1.f / (float)N_V) * Wo0[t] + se * (1.f / (float)N_E) * Wo1[t];
  __syncthreads();
  for (int o = 64; o > 0; o >>= 1) {
    if (t < o) red[t] += red[t + o];
    __syncthreads();
  }
  if (t == 0) out[0] = red[0] + bo0[0] + bo1[0];
}

extern "C" void kernel_launch(void* const* d_in, const int* in_sizes, int n_in,
                              void* d_out, int out_size, void* d_ws, size_t ws_size,
                              hipStream_t stream) {
  const float* x0in = (const float*)d_in[0];
  const int* rows   = (const int*)d_in[2];
  const int* cols   = (const int*)d_in[3];
  const float* W0   = (const float*)d_in[4];
  const float* b0   = (const float*)d_in[5];
  const float* Wl0  = (const float*)d_in[8];
  const float* bl0  = (const float*)d_in[9];
  const float* Wl1  = (const float*)d_in[10];
  const float* bl1  = (const float*)d_in[11];
  const float* Wo0  = (const float*)d_in[12];
  const float* bo0  = (const float*)d_in[13];
  const float* Wo1  = (const float*)d_in[14];
  const float* bo1  = (const float*)d_in[15];
  float* out = (float*)d_out;
  char* ws = (char*)d_ws;

  // ---- workspace layout (only [0, 4100) needs zeroing) ----
  int*    cntR  = (int*)(ws + 0);            // 391 ints (pad 2048)
  int*    cntC  = (int*)(ws + 2048);         // 391 ints (pad 2048)
  float*  qsum  = (float*)(ws + 4096);       // 4       -> memset [0, 4100)
  float*  rdegf = (float*)(ws + 8192);       // 400,000
  float*  invdg = (float*)(ws + 408192);     // 400,000
  float*  Wv    = (float*)(ws + 808192);     // 400,000
  float*  Sv    = (float*)(ws + 1208192);    // 400,000
  float*  WvD   = (float*)(ws + 1608192);    // 400,000
  float*  Z2    = (float*)(ws + 2008192);    // 400,000
  float2* wn    = (float2*)(ws + 2408192);   // 1,600,000
  float*  zM    = (float*)(ws + 4008192);    // 800,000
  float*  W0f   = (float*)(ws + 4808192);    // 7,168
  float*  b0f   = (float*)(ws + 4815360);    // 512
  float*  partialT = (float*)(ws + 4815872); // 512*391*4 = 800,768
  float*  cs    = (float*)(ws + 5616640);    // 2,048
  unsigned* binnedR = (unsigned*)(ws + 5618688);  // 391*3072*4 = 4,804,608
  unsigned* binnedC = (unsigned*)(ws + 10423296); // 4,804,608
  // total: 15,227,904 B

  const int NBLK = (N_V + 255) / 256;        // 391

  hipMemsetAsync(ws, 0, 4100, stream);
  k_bin2<<<dim3(196 + D_IN + 1), dim3(1024), 0, stream>>>(rows, cols, W0, b0, Wl0, bl0,
                                                          W0f, b0f, binnedR, cntR, binnedC, cntC);
  k_fhist<<<dim3(NB_R), dim3(512), 0, stream>>>(binnedR, cntR, rdegf, invdg);
  k_fA<<<dim3(NB_C), dim3(512), 0, stream>>>(binnedC, cntC, invdg, wn, qsum);
  k_fB<<<dim3(NB_R), dim3(512), 0, stream>>>(binnedR, cntR, wn, invdg, Wv, Sv, WvD);
  k_fC<<<dim3(NB_C), dim3(512), 0, stream>>>(binnedC, cntC, WvD, zM);
  k_fD<<<dim3(NB_R), dim3(512), 0, stream>>>(binnedR, cntR, zM, Z2);
  k_dense<<<dim3(NBLK), dim3(256), 0, stream>>>(x0in, W0f, b0f, rdegf, Wv, Sv, Z2, partialT, NBLK);
  k_red<<<dim3(128), dim3(256), 0, stream>>>(partialT, NBLK, cs);
  k_final<<<dim3(1), dim3(128), 0, stream>>>(cs, qsum, Wl1, bl1, Wo0, bo0, Wo1, bo1, out);
}